// Round 5
// baseline (474.229 us; speedup 1.0000x reference)
//
#include <hip/hip_runtime.h>
#include <hip/hip_bf16.h>

// PatchAttentionLayer R11 (= R10 resubmit + spin bound 2^20 -> 2^17).
//   grid 512 = 2 blocks/CU (guaranteed by __launch_bounds__(256,2) + 37.4KB LDS)
//   barrier polling via relaxed device-scope atomic LOAD (no RMW ping-pong)
//   Phase A/E: exactly 1 virtual tile per block (no serial doubling)
//   Phase C: split into C1/C2/C3 across 36 blocks, reduction depth 256->64,
//            partials atomicAdd'ed into accumulators in the dead Pg region
//   Phase D: Z/F single 32KB LDS buffer (F fully in regs before overwrite)
// 2 dispatches total (64B memset + mono).

#define BB 8
#define CC 256
#define NPIX 4096
#define PTOT 32768
#define EPSV 1e-5f
#define SCALEV 0.125f

// ---- workspace layout (float offsets) ----
#define OFF_PG    0L          // gram partials (dead after Phase A; accumulators live here)
#define OFF_SP    3145728L
#define OFF_S     3162112L
#define OFF_GHAT  3164160L
#define OFF_XBAR  3229696L
#define OFF_WP    3229952L
#define OFF_WKTF  3426560L
#define OFF_WVTF  3492096L
#define OFF_CVEC  3557632L
#define OFF_OFFV  3565056L
#define OFF_GBF   3567104L    // 8*65536 ushort
#define OFF_WQT   3829248L
#define OFF_WKT   3862016L
#define OFF_WVB   3894784L
#define OFF_TBF   4222464L    // 8*65536 ushort
#define OFF_CNT   4484608L    // barrier counter (16 floats reserved)

// accumulator offsets inside the (dead) Pg region, in floats:
#define ACC_U  0      // 8*256
#define ACC_W  2048   // 8*256
#define ACC_Y  4096   // 256
#define ACC_R  4352   // 256
#define ACC_H  4608   // 8*256
#define ACC_G  6656   // 8*256
#define ACC_N  8704

typedef __attribute__((ext_vector_type(8))) short short8;
typedef __attribute__((ext_vector_type(4))) float f32x4;

#define MFMA16(a, b, c) __builtin_amdgcn_mfma_f32_16x16x32_bf16((a), (b), (c), 0, 0, 0)

__device__ __forceinline__ ushort f2bf(float f) {
    union { float f; unsigned u; } v; v.f = f;
    const unsigned r = (v.u + 0x7FFFu + ((v.u >> 16) & 1u)) >> 16;
    return (ushort)r;
}

__device__ __forceinline__ float bf2f(ushort u) {
    union { unsigned u; float f; } v; v.u = ((unsigned)u) << 16;
    return v.f;
}

__device__ __forceinline__ ushort2 f2bf2(float a, float b) {
    __hip_bfloat162 h = __float22bfloat162_rn(float2{a, b});
    union { __hip_bfloat162 h; ushort2 u; } v; v.h = h;
    return v.u;
}

__device__ __forceinline__ float block_reduce(float v, float* red, int tid) {
    red[tid] = v; __syncthreads();
    for (int st = 128; st > 0; st >>= 1) {
        if (tid < st) red[tid] += red[tid + st];
        __syncthreads();
    }
    float r = red[0]; __syncthreads();
    return r;
}

__device__ __forceinline__ float2 wred2(float a, float b, float* red8, int tid) {
    #pragma unroll
    for (int s = 32; s > 0; s >>= 1) {
        a += __shfl_xor(a, s);
        b += __shfl_xor(b, s);
    }
    if ((tid & 63) == 0) { red8[(tid >> 6) * 2] = a; red8[(tid >> 6) * 2 + 1] = b; }
    __syncthreads();
    const float ra = red8[0] + red8[2] + red8[4] + red8[6];
    const float rb = red8[1] + red8[3] + red8[5] + red8[7];
    __syncthreads();
    return float2{ra, rb};
}

// grid barrier: increment = atomicAdd (RMW, once per block); poll = relaxed
// device-scope atomic LOAD (served by home L2 slice, no exclusive ping-pong).
// Bounded spin (2^17 polls ~ 28 ms) -> any co-residency pathology fails FAST
// and visibly (wrong results) instead of a container timeout.
__device__ __forceinline__ void gbar(unsigned* cnt, unsigned target) {
    __syncthreads();
    if (threadIdx.x == 0) {
        __threadfence();
        atomicAdd(cnt, 1u);
        unsigned spins = 0;
        while (__hip_atomic_load(cnt, __ATOMIC_RELAXED, __HIP_MEMORY_SCOPE_AGENT) < target
               && ++spins < (1u << 17))
            __builtin_amdgcn_s_sleep(8);
        __threadfence();
    }
    __syncthreads();
}

union SmemU {
    struct { ushort Ab[128 * 72]; ushort Bb[128 * 72]; float rs[128]; } g; // 37376 B (max)
    struct { float tile[32][33]; } rm;
    struct { float wr4[4][256]; float red8[8]; } st;
    struct { float sh[256], wl[256], yl[256], gyl[256],
                   red[256], cqs[256], cks[256]; } vx;
    struct { ushort zt[64 * 256]; } ch;                                    // 32768 B
    struct { ushort Bs[64 * 264]; } op;                                    // 33792 B
};

// 256x64 MFMA tile: D[row,col] = sum_k A[row,k]*B[col,k]; 4 waves on rows.
__device__ __forceinline__ void mm256x64(f32x4 acc[4][4],
                                         const ushort* __restrict__ Aglob,
                                         const ushort* __restrict__ Bglob,
                                         const ushort* Blds,
                                         int wave, int m, int qq) {
    const int q8 = qq * 8;
    #pragma unroll
    for (int kk = 0; kk < 8; ++kk) {
        short8 af[4], bv[4];
        #pragma unroll
        for (int a = 0; a < 4; ++a)
            af[a] = *(const short8*)&Aglob[(long)(wave * 64 + a * 16 + m) * 256 + kk * 32 + q8];
        #pragma unroll
        for (int q = 0; q < 4; ++q) {
            const int col = q * 16 + m;
            if (Blds) bv[q] = *(const short8*)&Blds[col * 256 + ((kk * 32 + q8) ^ ((col & 7) << 3))];
            else      bv[q] = *(const short8*)&Bglob[(long)col * 256 + kk * 32 + q8];
        }
        #pragma unroll
        for (int a = 0; a < 4; ++a)
            #pragma unroll
            for (int q = 0; q < 4; ++q)
                acc[a][q] = MFMA16(af[a], bv[q], acc[a][q]);
    }
}

// store D (256x64) -> LDS as L[col][row] bf16, XOR-swizzled on row index.
__device__ __forceinline__ void st_lds(ushort* L, f32x4 acc[4][4],
                                       int wave, int m, int qq) {
    #pragma unroll
    for (int a = 0; a < 4; ++a)
        #pragma unroll
        for (int q = 0; q < 4; ++q) {
            const int col = q * 16 + m;
            const int rowb = wave * 64 + a * 16 + qq * 4;
            const ushort2 p01 = f2bf2(acc[a][q][0], acc[a][q][1]);
            const ushort2 p23 = f2bf2(acc[a][q][2], acc[a][q][3]);
            ushort4 w4; w4.x = p01.x; w4.y = p01.y; w4.z = p23.x; w4.w = p23.y;
            *(ushort4*)&L[col * 256 + (rowb ^ ((col & 7) << 3))] = w4;
        }
}

__global__ __launch_bounds__(256, 2) void mono(
        const float* __restrict__ x,
        const float* __restrict__ Wq, const float* __restrict__ bq,
        const float* __restrict__ gq, const float* __restrict__ betaq,
        const float* __restrict__ Wk, const float* __restrict__ bk,
        const float* __restrict__ gk, const float* __restrict__ betak,
        const float* __restrict__ Wv, const float* __restrict__ bv,
        const float* __restrict__ gv, const float* __restrict__ betav,
        float* __restrict__ out,
        float* __restrict__ Pg, float* __restrict__ Sp, float* __restrict__ S,
        float* __restrict__ Ghat, float* __restrict__ xbar,
        float* __restrict__ Wp, float* __restrict__ WkTf, float* __restrict__ WvTf,
        float* __restrict__ cvec, float* __restrict__ offv,
        ushort* __restrict__ Gbf, ushort* __restrict__ WqT, ushort* __restrict__ WkT,
        ushort* __restrict__ Wvb, ushort* __restrict__ Tbf,
        unsigned* __restrict__ cnt) {
    __shared__ SmemU sm;
    const int blk = blockIdx.x, tid = threadIdx.x;
    const unsigned NB = gridDim.x;
    float* Acc = Pg;   // accumulators alias the (later-dead) Pg region

    // ================= Phase 0: gram (+ Ghat zero) =================
    if (blk < 64) {
        #pragma unroll
        for (int i = 0; i < 4; ++i) Ghat[blk * 1024 + i * 256 + tid] = 0.f;
    }
    if (blk < 192) {
        const int ks = blk & 7, b = (blk >> 3) & 7, tt = blk >> 6;
        const int it = (tt == 1) ? 1 : 0;
        const int jt = (tt == 0) ? 0 : 1;
        const bool diag = (tt < 2);
        const int i0 = it * 128, j0 = jt * 128, k0 = ks * 512;
        const float* xb = x + (long)b * CC * NPIX;
        const int c = tid & 15, rp = tid >> 4;
        const int wave = tid >> 6, lane = tid & 63;
        const int wr = (wave >> 1) * 64, wc = (wave & 1) * 64;
        const int m = lane & 15, q8 = (lane >> 4) * 8;

        if (tid < 128) sm.g.rs[tid] = 0.f;
        float rloc[8] = {};
        f32x4 acc[4][4];
        #pragma unroll
        for (int a = 0; a < 4; ++a)
            #pragma unroll
            for (int q = 0; q < 4; ++q) acc[a][q] = (f32x4){0.f, 0.f, 0.f, 0.f};

        const float* Abase = xb + (long)i0 * NPIX + k0 + c * 4;
        const float* Bbase = xb + (long)j0 * NPIX + k0 + c * 4;

        float4 va[8], vb[8];
        #pragma unroll
        for (int pp = 0; pp < 8; ++pp)
            va[pp] = *(const float4*)&Abase[(long)(pp * 16 + rp) * NPIX];
        if (!diag) {
            #pragma unroll
            for (int pp = 0; pp < 8; ++pp)
                vb[pp] = *(const float4*)&Bbase[(long)(pp * 16 + rp) * NPIX];
        }

        for (int kc = 0; kc < 512; kc += 64) {
            __syncthreads();
            #pragma unroll
            for (int pp = 0; pp < 8; ++pp) {
                const int row = pp * 16 + rp;
                const float4 v = va[pp];
                rloc[pp] += v.x + v.y + v.z + v.w;
                const ushort2 w01 = f2bf2(v.x, v.y);
                const ushort2 w23 = f2bf2(v.z, v.w);
                ushort4 w; w.x = w01.x; w.y = w01.y; w.z = w23.x; w.w = w23.y;
                *(ushort4*)&sm.g.Ab[row * 72 + c * 4] = w;
            }
            if (!diag) {
                #pragma unroll
                for (int pp = 0; pp < 8; ++pp) {
                    const int row = pp * 16 + rp;
                    const float4 v = vb[pp];
                    const ushort2 w01 = f2bf2(v.x, v.y);
                    const ushort2 w23 = f2bf2(v.z, v.w);
                    ushort4 w; w.x = w01.x; w.y = w01.y; w.z = w23.x; w.w = w23.y;
                    *(ushort4*)&sm.g.Bb[row * 72 + c * 4] = w;
                }
            }
            const int kn = kc + 64;
            if (kn < 512) {
                #pragma unroll
                for (int pp = 0; pp < 8; ++pp)
                    va[pp] = *(const float4*)&Abase[(long)(pp * 16 + rp) * NPIX + kn];
                if (!diag) {
                    #pragma unroll
                    for (int pp = 0; pp < 8; ++pp)
                        vb[pp] = *(const float4*)&Bbase[(long)(pp * 16 + rp) * NPIX + kn];
                }
            }
            __syncthreads();
            const ushort* Bsrc = diag ? sm.g.Ab : sm.g.Bb;
            #pragma unroll
            for (int kk = 0; kk < 2; ++kk) {
                short8 af[4], bfv[4];
                #pragma unroll
                for (int a = 0; a < 4; ++a)
                    af[a] = *(const short8*)&sm.g.Ab[(wr + a * 16 + m) * 72 + kk * 32 + q8];
                #pragma unroll
                for (int q = 0; q < 4; ++q)
                    bfv[q] = *(const short8*)&Bsrc[(wc + q * 16 + m) * 72 + kk * 32 + q8];
                #pragma unroll
                for (int a = 0; a < 4; ++a)
                    #pragma unroll
                    for (int q = 0; q < 4; ++q)
                        acc[a][q] = MFMA16(af[a], bfv[q], acc[a][q]);
            }
        }
        if (diag) {
            #pragma unroll
            for (int pp = 0; pp < 8; ++pp) atomicAdd(&sm.g.rs[pp * 16 + rp], rloc[pp]);
            __syncthreads();
            if (tid < 128) Sp[(((long)ks * 8 + b) * 2 + it) * 128 + tid] = sm.g.rs[tid];
        }
        float* Pt = Pg + (((long)ks * 8 + b) * 3 + tt) * 16384;
        const int rq = (lane >> 4) * 4;
        #pragma unroll
        for (int a = 0; a < 4; ++a) {
            #pragma unroll
            for (int q = 0; q < 4; ++q) {
                const int col = wc + q * 16 + m;
                #pragma unroll
                for (int reg = 0; reg < 4; ++reg)
                    Pt[(long)(wr + a * 16 + rq + reg) * 128 + col] = acc[a][q][reg];
            }
        }
    }
    gbar(cnt, NB * 1);

    // ================= Phase A: reduce partials (1 tile/block) =================
    if (blk <= 384) {
        const int v = blk;
        if (v == 384) {
            const int it2 = tid >> 7, rr = tid & 127;
            float xacc = 0.f;
            for (int b = 0; b < BB; ++b) {
                float acc = 0.f;
                #pragma unroll
                for (int ks = 0; ks < 8; ++ks)
                    acc += Sp[(((long)ks * 8 + b) * 2 + it2) * 128 + rr];
                S[b * 256 + tid] = acc;
                xacc += acc;
            }
            xbar[tid] = xacc * (1.0f / PTOT);
        } else {
            const int tt = v >> 7;
            const int sub = (v >> 3) & 15;
            const int b = v & 7;
            const int sr = (sub >> 2) * 32, sc = (sub & 3) * 32;
            const int it = (tt == 1) ? 1 : 0;
            const int jt = (tt == 0) ? 0 : 1;
            const bool offd = (tt == 2);
            const int gi0 = it * 128 + sr, gj0 = jt * 128 + sc;
            const int r = tid >> 3, c4 = (tid & 7) * 4;
            const float inv = 1.0f / PTOT;

            float s0 = 0.f, s1 = 0.f, s2 = 0.f, s3 = 0.f;
            #pragma unroll
            for (int ks = 0; ks < 8; ++ks) {
                const float4 pv = *(const float4*)&Pg[(((long)ks * 8 + b) * 3 + tt) * 16384
                                                      + (long)(sr + r) * 128 + sc + c4];
                s0 += pv.x; s1 += pv.y; s2 += pv.z; s3 += pv.w;
            }
            ushort4 w;
            w.x = f2bf(s0); w.y = f2bf(s1); w.z = f2bf(s2); w.w = f2bf(s3);
            *(ushort4*)&Gbf[(long)b * 65536 + (long)(gi0 + r) * 256 + gj0 + c4] = w;
            float* gd = &Ghat[(long)(gi0 + r) * 256 + gj0 + c4];
            atomicAdd(gd + 0, s0 * inv);
            atomicAdd(gd + 1, s1 * inv);
            atomicAdd(gd + 2, s2 * inv);
            atomicAdd(gd + 3, s3 * inv);
            if (offd) {
                sm.rm.tile[r][c4 + 0] = s0; sm.rm.tile[r][c4 + 1] = s1;
                sm.rm.tile[r][c4 + 2] = s2; sm.rm.tile[r][c4 + 3] = s3;
                __syncthreads();
                const float t0 = sm.rm.tile[c4 + 0][r], t1 = sm.rm.tile[c4 + 1][r];
                const float t2 = sm.rm.tile[c4 + 2][r], t3 = sm.rm.tile[c4 + 3][r];
                ushort4 tw;
                tw.x = f2bf(t0); tw.y = f2bf(t1); tw.z = f2bf(t2); tw.w = f2bf(t3);
                *(ushort4*)&Gbf[(long)b * 65536 + (long)(gj0 + r) * 256 + gi0 + c4] = tw;
                float* gm = &Ghat[(long)(gj0 + r) * 256 + gi0 + c4];
                atomicAdd(gm + 0, t0 * inv);
                atomicAdd(gm + 1, t1 * inv);
                atomicAdd(gm + 2, t2 * inv);
                atomicAdd(gm + 3, t3 * inv);
            }
        }
    }
    gbar(cnt, NB * 2);

    // ================= Phase B: BN stats + accumulator zeroing =================
    if (blk < 192) {
        const int og = blk & 63, t = blk >> 6;
        const int o0 = og * 4;
        const float* Wt  = t == 0 ? Wq : (t == 1 ? Wk : Wv);
        const float* bt  = t == 0 ? bq : (t == 1 ? bk : bv);
        const float* gt  = t == 0 ? gq : (t == 1 ? gk : gv);
        const float* bet = t == 0 ? betaq : (t == 1 ? betak : betav);
        #pragma unroll
        for (int i = 0; i < 4; ++i) sm.st.wr4[i][tid] = Wt[(o0 + i) * 256 + tid];
        const float xb = xbar[tid];
        __syncthreads();
        const float* grow = Ghat + (long)tid * 256;
        float tj[4] = {0.f, 0.f, 0.f, 0.f};
        #pragma unroll 8
        for (int k = 0; k < 256; k += 4) {
            const float4 g = *(const float4*)&grow[k];
            #pragma unroll
            for (int i = 0; i < 4; ++i)
                tj[i] += g.x * sm.st.wr4[i][k]     + g.y * sm.st.wr4[i][k + 1]
                       + g.z * sm.st.wr4[i][k + 2] + g.w * sm.st.wr4[i][k + 3];
        }
        #pragma unroll
        for (int i = 0; i < 4; ++i) {
            const int o = o0 + i;
            const float wv = sm.st.wr4[i][tid];
            const float2 qw = wred2(wv * tj[i], wv * xb, sm.st.red8, tid);
            const float bo = bt[o];
            const float mu = qw.y + bo;
            const float var = qw.x + 2.f * bo * mu - bo * bo - mu * mu;
            const float a = gt[o] * rsqrtf(var + EPSV);
            const float wpv = a * wv;
            Wp[(long)t * 65536 + o * 256 + tid] = wpv;
            const ushort wb = f2bf(wpv);
            if (t == 0) {
                WqT[(long)tid * 256 + o] = wb;
            } else if (t == 1) {
                WkT[(long)tid * 256 + o] = wb;
                WkTf[(long)tid * 256 + o] = wpv;
            } else {
                Wvb[(long)o * 256 + tid] = wb;
                WvTf[(long)tid * 256 + o] = wpv;
            }
            if (tid == 0) cvec[t * 256 + o] = a * (bo - mu) + bet[o];
        }
    } else if (blk < 226) {
        const int idx = (blk - 192) * 256 + tid;
        if (idx < ACC_N) Acc[idx] = 0.f;
    }
    gbar(cnt, NB * 3);

    // ================= Phase C1: partial {u,w} (32 blocks), {y,r} (4) =========
    if (blk < 32) {
        const int b = blk >> 2, i0b = (blk & 3) * 64;
        if (tid < 64) sm.vx.sh[tid] = S[b * 256 + i0b + tid];
        __syncthreads();
        float uu = 0.f, ww = 0.f;
        #pragma unroll 8
        for (int i = 0; i < 64; ++i) {
            const float sv = sm.vx.sh[i];
            uu += WvTf[(long)(i0b + i) * 256 + tid] * sv;
            ww += WkTf[(long)(i0b + i) * 256 + tid] * sv;
        }
        atomicAdd(&Acc[ACC_U + b * 256 + tid], uu);
        atomicAdd(&Acc[ACC_W + b * 256 + tid], ww);
    } else if (blk < 36) {
        const int o0 = (blk - 32) * 64;
        if (tid < 64) {
            sm.vx.cqs[tid] = cvec[o0 + tid];
            sm.vx.cks[tid] = cvec[256 + o0 + tid];
        }
        __syncthreads();
        float yy = 0.f, rr = 0.f;
        #pragma unroll 8
        for (int i = 0; i < 64; ++i) {
            yy += Wp[65536L + (long)(o0 + i) * 256 + tid] * sm.vx.cqs[i];
            rr += Wp[(long)(o0 + i) * 256 + tid] * sm.vx.cks[i];
        }
        atomicAdd(&Acc[ACC_Y + tid], yy);
        atomicAdd(&Acc[ACC_R + tid], rr);
    }
    gbar(cnt, NB * 4);

    // ================= Phase C2: partial {h, g} (32 blocks) ===================
    if (blk < 32) {
        const int b = blk >> 2, o0 = (blk & 3) * 64;
        if (tid < 64) {
            sm.vx.wl[tid] = Acc[ACC_W + b * 256 + o0 + tid];
            sm.vx.yl[tid] = Acc[ACC_Y + o0 + tid];
        }
        __syncthreads();
        float hh = 0.f, gg = 0.f;
        #pragma unroll 8
        for (int i = 0; i < 64; ++i) {
            hh += Wp[(long)(o0 + i) * 256 + tid] * sm.vx.wl[i];
            gg += bf2f(Gbf[(long)b * 65536 + (long)(o0 + i) * 256 + tid]) * sm.vx.yl[i];
        }
        atomicAdd(&Acc[ACC_H + b * 256 + tid], hh);
        atomicAdd(&Acc[ACC_G + b * 256 + tid], gg);
    }
    gbar(cnt, NB * 5);

    // ================= Phase C3: vg + scalars -> offv (8 blocks) ==============
    if (blk < 8) {
        const int b = blk;
        sm.vx.cqs[tid] = cvec[tid];
        sm.vx.cks[tid] = cvec[256 + tid];
        sm.vx.wl[tid]  = Acc[ACC_W + b * 256 + tid];
        sm.vx.gyl[tid] = Acc[ACC_G + b * 256 + tid];
        __syncthreads();
        float vg = 0.f;
        #pragma unroll 8
        for (int j = 0; j < 256; ++j) vg += WvTf[(long)j * 256 + tid] * sm.vx.gyl[j];
        const float cv = cvec[512 + tid];
        const float uu = Acc[ACC_U + b * 256 + tid];
        const float dkq = block_reduce(sm.vx.cqs[tid] * sm.vx.cks[tid], sm.vx.red, tid);
        const float dwq = block_reduce(sm.vx.wl[tid] * sm.vx.cqs[tid], sm.vx.red, tid);
        offv[b * 256 + tid] = SCALEV * (vg + uu * dkq + cv * (dwq + 4096.0f * dkq));
    }
    gbar(cnt, NB * 6);

    // ================= Phase D: fused Z->F->T chain (32 blocks) ===============
    if (blk < 32) {
        const int b = blk >> 2, j0 = (blk & 3) * 64;
        const int wave = tid >> 6, lane = tid & 63;
        const int m = lane & 15, qq = lane >> 4;
        f32x4 acc[4][4];

        // step 1: zt <- Z^T slice (cols j0..j0+63)
        #pragma unroll
        for (int a = 0; a < 4; ++a)
            #pragma unroll
            for (int q = 0; q < 4; ++q) acc[a][q] = (f32x4){0.f, 0.f, 0.f, 0.f};
        mm256x64(acc, WkT, WqT + (long)j0 * 256, nullptr, wave, m, qq);
        st_lds(sm.ch.zt, acc, wave, m, qq);
        __syncthreads();

        // step 2: F slice fully into regs (reads zt), then overwrite zt with F
        #pragma unroll
        for (int a = 0; a < 4; ++a)
            #pragma unroll
            for (int q = 0; q < 4; ++q) acc[a][q] = (f32x4){0.f, 0.f, 0.f, 0.f};
        mm256x64(acc, Gbf + (long)b * 65536, nullptr, sm.ch.zt, wave, m, qq);
        __syncthreads();                  // all zt reads complete
        st_lds(sm.ch.zt, acc, wave, m, qq);
        __syncthreads();

        // step 3: T slice = Wv' * F + rank-1 epilogue -> Tbf
        #pragma unroll
        for (int a = 0; a < 4; ++a)
            #pragma unroll
            for (int q = 0; q < 4; ++q) acc[a][q] = (f32x4){0.f, 0.f, 0.f, 0.f};
        mm256x64(acc, Wvb, nullptr, sm.ch.zt, wave, m, qq);
        const int rq4 = qq * 4;
        #pragma unroll
        for (int a = 0; a < 4; ++a) {
            #pragma unroll
            for (int q = 0; q < 4; ++q) {
                const int cg = j0 + q * 16 + m;
                const float rv = Acc[ACC_R + cg];
                const float t2 = Acc[ACC_H + b * 256 + cg] + 4096.0f * rv;
                #pragma unroll
                for (int reg = 0; reg < 4; ++reg) {
                    const int row = wave * 64 + a * 16 + rq4 + reg;
                    const float val = SCALEV * (acc[a][q][reg]
                                                + Acc[ACC_U + b * 256 + row] * rv
                                                + cvec[512 + row] * t2);
                    Tbf[(long)b * 65536 + (long)row * 256 + cg] = f2bf(val);
                }
            }
        }
    }
    gbar(cnt, NB * 7);

    // ================= Phase E: out = T x + off (1 tile/block) ================
    {
        const int p0 = (blk & 63) * 64;
        const int b = blk >> 6;
        const float* xb = x + (long)b * CC * NPIX;
        const ushort* Tb = Tbf + (long)b * 65536;

        const int c = tid & 15, kq = tid >> 4;
        #pragma unroll
        for (int kt = 0; kt < 4; ++kt) {
            const int k4 = kt * 64 + kq * 4;
            const int p = c * 4;
            const float4 v0 = *(const float4*)&xb[(long)(k4 + 0) * NPIX + p0 + p];
            const float4 v1 = *(const float4*)&xb[(long)(k4 + 1) * NPIX + p0 + p];
            const float4 v2 = *(const float4*)&xb[(long)(k4 + 2) * NPIX + p0 + p];
            const float4 v3 = *(const float4*)&xb[(long)(k4 + 3) * NPIX + p0 + p];
            ushort2 a01, a23;
            ushort4 w;
            a01 = f2bf2(v0.x, v1.x); a23 = f2bf2(v2.x, v3.x);
            w.x = a01.x; w.y = a01.y; w.z = a23.x; w.w = a23.y;
            *(ushort4*)&sm.op.Bs[(p + 0) * 264 + k4] = w;
            a01 = f2bf2(v0.y, v1.y); a23 = f2bf2(v2.y, v3.y);
            w.x = a01.x; w.y = a01.y; w.z = a23.x; w.w = a23.y;
            *(ushort4*)&sm.op.Bs[(p + 1) * 264 + k4] = w;
            a01 = f2bf2(v0.z, v1.z); a23 = f2bf2(v2.z, v3.z);
            w.x = a01.x; w.y = a01.y; w.z = a23.x; w.w = a23.y;
            *(ushort4*)&sm.op.Bs[(p + 2) * 264 + k4] = w;
            a01 = f2bf2(v0.w, v1.w); a23 = f2bf2(v2.w, v3.w);
            w.x = a01.x; w.y = a01.y; w.z = a23.x; w.w = a23.y;
            *(ushort4*)&sm.op.Bs[(p + 3) * 264 + k4] = w;
        }
        __syncthreads();

        const int wave = tid >> 6, lane = tid & 63;
        const int wr = wave * 64;
        const int m = lane & 15, q8 = (lane >> 4) * 8;
        f32x4 acc[4][4];
        #pragma unroll
        for (int a = 0; a < 4; ++a)
            #pragma unroll
            for (int q = 0; q < 4; ++q) acc[a][q] = (f32x4){0.f, 0.f, 0.f, 0.f};

        #pragma unroll
        for (int kk = 0; kk < 8; ++kk) {
            short8 af[4], bfv[4];
            #pragma unroll
            for (int a = 0; a < 4; ++a)
                af[a] = *(const short8*)&Tb[(long)(wr + a * 16 + m) * 256 + kk * 32 + q8];
            #pragma unroll
            for (int q = 0; q < 4; ++q)
                bfv[q] = *(const short8*)&sm.op.Bs[(q * 16 + m) * 264 + kk * 32 + q8];
            #pragma unroll
            for (int a = 0; a < 4; ++a)
                #pragma unroll
                for (int q = 0; q < 4; ++q)
                    acc[a][q] = MFMA16(af[a], bfv[q], acc[a][q]);
        }

        const int rq = (lane >> 4) * 4;
        #pragma unroll
        for (int a = 0; a < 4; ++a) {
            #pragma unroll
            for (int reg = 0; reg < 4; ++reg) {
                const int row = wr + a * 16 + rq + reg;
                const float off_ = offv[b * CC + row];
                float* orow = &out[((long)b * CC + row) * NPIX + p0];
                #pragma unroll
                for (int q = 0; q < 4; ++q)
                    orow[q * 16 + m] = acc[a][q][reg] + off_;
            }
        }
    }
}

extern "C" void kernel_launch(void* const* d_in, const int* in_sizes, int n_in,
                              void* d_out, int out_size, void* d_ws, size_t ws_size,
                              hipStream_t stream) {
    const float* x     = (const float*)d_in[0];
    const float* Wq    = (const float*)d_in[1];
    const float* bq    = (const float*)d_in[2];
    const float* gq    = (const float*)d_in[3];
    const float* betaq = (const float*)d_in[4];
    const float* Wk    = (const float*)d_in[5];
    const float* bk    = (const float*)d_in[6];
    const float* gk    = (const float*)d_in[7];
    const float* betak = (const float*)d_in[8];
    const float* Wv    = (const float*)d_in[9];
    const float* bv    = (const float*)d_in[10];
    const float* gv    = (const float*)d_in[11];
    const float* betav = (const float*)d_in[12];
    float* ws = (float*)d_ws;

    float*  Pg   = ws + OFF_PG;
    float*  Sp   = ws + OFF_SP;
    float*  S    = ws + OFF_S;
    float*  Ghat = ws + OFF_GHAT;
    float*  Xbar = ws + OFF_XBAR;
    float*  Wp   = ws + OFF_WP;
    float*  WkTf = ws + OFF_WKTF;
    float*  WvTf = ws + OFF_WVTF;
    float*  cvec = ws + OFF_CVEC;
    float*  OffV = ws + OFF_OFFV;
    ushort* Gbf  = (ushort*)(ws + OFF_GBF);
    ushort* WqT  = (ushort*)(ws + OFF_WQT);
    ushort* WkT  = (ushort*)(ws + OFF_WKT);
    ushort* Wvb  = (ushort*)(ws + OFF_WVB);
    ushort* Tbf  = (ushort*)(ws + OFF_TBF);
    unsigned* Cnt = (unsigned*)(ws + OFF_CNT);

    hipMemsetAsync((void*)Cnt, 0, 64, stream);
    mono<<<512, 256, 0, stream>>>(x, Wq, bq, gq, betaq, Wk, bk, gk, betak,
                                  Wv, bv, gv, betav, (float*)d_out,
                                  Pg, Sp, S, Ghat, Xbar, Wp, WkTf, WvTf, cvec,
                                  OffV, Gbf, WqT, WkT, Wvb, Tbf, Cnt);
}

// Round 6
// 446.257 us; speedup vs baseline: 1.0627x; 1.0627x over previous
//
#include <hip/hip_runtime.h>
#include <hip/hip_bf16.h>

// PatchAttentionLayer R12: persistent kernel v3 — epoch barriers.
//   Diagnosis R9/R11: count-polling grid barrier ~24-49us each (pollers and
//   arrivals fight over ONE cacheline). Fix: count line + epoch line; last
//   arriver bumps epoch once; pollers read the write-once epoch line.
//   grid 256 (1 block/CU, proven work distribution)
//   gram: atomicAdd fp32 G directly (no Pg partials; G zeroed by memset)
//   A: 48 plain-read works -> Gbf/Ghat (no atomics) + S/xbar
//   C1: u,w,y,r partials + Z GEMM (once, 4 blocks) ; C2: h,g ; C3: offv
//   C1->C2->C3->D chained with 40-block mini-barriers (2nd count/epoch pair)
//   D: F = G Z (Z from global) -> LDS ; T = Wv' F + epilogue -> Tbf
//   E: out = T x + off (2 tiles/block)
// 3 dispatches: memset(G) + memset(barrier) + mono.

#define BB 8
#define CC 256
#define NPIX 4096
#define PTOT 32768
#define EPSV 1e-5f
#define SCALEV 0.125f

// ---- workspace layout (float offsets) ----
#define OFF_GFP   0L          // 24*16384 = 393216 fp32 atomic-accumulated G
#define OFF_ACC   1048576L    // small accumulators (8704 floats)
#define OFF_SP    3145728L
#define OFF_S     3162112L
#define OFF_GHAT  3164160L
#define OFF_XBAR  3229696L
#define OFF_WP    3229952L
#define OFF_WKTF  3426560L
#define OFF_WVTF  3492096L
#define OFF_CVEC  3557632L
#define OFF_OFFV  3565056L
#define OFF_GBF   3567104L    // 8*65536 ushort
#define OFF_WQT   3829248L
#define OFF_WKT   3862016L
#define OFF_WVB   3894784L
#define OFF_ZT    3927552L    // Z^T bf16 [col][row]
#define OFF_TBF   4222464L    // 8*65536 ushort
#define OFF_CNT   4484608L    // 128 floats: fcnt@0, fep@+32, mcnt@+64, mep@+96

// accumulator offsets inside OFF_ACC, in floats:
#define ACC_U  0      // 8*256
#define ACC_W  2048   // 8*256
#define ACC_Y  4096   // 256
#define ACC_R  4352   // 256
#define ACC_H  4608   // 8*256
#define ACC_G  6656   // 8*256
#define ACC_N  8704

typedef __attribute__((ext_vector_type(8))) short short8;
typedef __attribute__((ext_vector_type(4))) float f32x4;

#define MFMA16(a, b, c) __builtin_amdgcn_mfma_f32_16x16x32_bf16((a), (b), (c), 0, 0, 0)

__device__ __forceinline__ ushort f2bf(float f) {
    union { float f; unsigned u; } v; v.f = f;
    const unsigned r = (v.u + 0x7FFFu + ((v.u >> 16) & 1u)) >> 16;
    return (ushort)r;
}

__device__ __forceinline__ float bf2f(ushort u) {
    union { unsigned u; float f; } v; v.u = ((unsigned)u) << 16;
    return v.f;
}

__device__ __forceinline__ ushort2 f2bf2(float a, float b) {
    __hip_bfloat162 h = __float22bfloat162_rn(float2{a, b});
    union { __hip_bfloat162 h; ushort2 u; } v; v.h = h;
    return v.u;
}

__device__ __forceinline__ float block_reduce(float v, float* red, int tid) {
    red[tid] = v; __syncthreads();
    for (int st = 128; st > 0; st >>= 1) {
        if (tid < st) red[tid] += red[tid + st];
        __syncthreads();
    }
    float r = red[0]; __syncthreads();
    return r;
}

__device__ __forceinline__ float2 wred2(float a, float b, float* red8, int tid) {
    #pragma unroll
    for (int s = 32; s > 0; s >>= 1) {
        a += __shfl_xor(a, s);
        b += __shfl_xor(b, s);
    }
    if ((tid & 63) == 0) { red8[(tid >> 6) * 2] = a; red8[(tid >> 6) * 2 + 1] = b; }
    __syncthreads();
    const float ra = red8[0] + red8[2] + red8[4] + red8[6];
    const float rb = red8[1] + red8[3] + red8[5] + red8[7];
    __syncthreads();
    return float2{ra, rb};
}

// Epoch barrier: arrivals RMW the count line; LAST arriver release-stores the
// epoch (a DIFFERENT cacheline, written once per barrier); others poll epoch.
// Pollers never touch the count line -> arrivals stream at L2 atomic speed.
// Bounded spin (2^15 * ~0.4us ~= 14ms) -> pathology fails fast and visibly.
__device__ __forceinline__ void gbar(unsigned* cnt, unsigned* ep,
                                     unsigned idx, unsigned nb) {
    __syncthreads();
    if (threadIdx.x == 0) {
        __threadfence();
        const unsigned old = __hip_atomic_fetch_add(cnt, 1u, __ATOMIC_RELAXED,
                                                    __HIP_MEMORY_SCOPE_AGENT);
        if (old + 1u == idx * nb) {
            __hip_atomic_store(ep, idx, __ATOMIC_RELEASE, __HIP_MEMORY_SCOPE_AGENT);
        } else {
            unsigned spins = 0;
            while (__hip_atomic_load(ep, __ATOMIC_ACQUIRE, __HIP_MEMORY_SCOPE_AGENT) < idx
                   && ++spins < (1u << 15))
                __builtin_amdgcn_s_sleep(16);
        }
        __threadfence();
    }
    __syncthreads();
}

union SmemU {
    struct { ushort Ab[128 * 72]; ushort Bb[128 * 72]; float rs[128]; } g; // 37376 B max
    struct { float tile[32][33]; } rm;
    struct { float wr4[4][256]; float red8[8]; } st;
    struct { float sh[256], wl[256], yl[256], gyl[256],
                   red[256], cqs[256], cks[256]; } vx;
    struct { ushort zt[64 * 256]; } ch;                                    // 32768 B
    struct { ushort Bs[64 * 264]; } op;                                    // 33792 B
};

// 256x64 MFMA tile: D[row,col] = sum_k A[row,k]*B[col,k]; 4 waves on rows.
__device__ __forceinline__ void mm256x64(f32x4 acc[4][4],
                                         const ushort* __restrict__ Aglob,
                                         const ushort* __restrict__ Bglob,
                                         const ushort* Blds,
                                         int wave, int m, int qq) {
    const int q8 = qq * 8;
    #pragma unroll
    for (int kk = 0; kk < 8; ++kk) {
        short8 af[4], bv[4];
        #pragma unroll
        for (int a = 0; a < 4; ++a)
            af[a] = *(const short8*)&Aglob[(long)(wave * 64 + a * 16 + m) * 256 + kk * 32 + q8];
        #pragma unroll
        for (int q = 0; q < 4; ++q) {
            const int col = q * 16 + m;
            if (Blds) bv[q] = *(const short8*)&Blds[col * 256 + ((kk * 32 + q8) ^ ((col & 7) << 3))];
            else      bv[q] = *(const short8*)&Bglob[(long)col * 256 + kk * 32 + q8];
        }
        #pragma unroll
        for (int a = 0; a < 4; ++a)
            #pragma unroll
            for (int q = 0; q < 4; ++q)
                acc[a][q] = MFMA16(af[a], bv[q], acc[a][q]);
    }
}

// store D (256x64) -> LDS as L[col][row] bf16, XOR-swizzled on row index.
__device__ __forceinline__ void st_lds(ushort* L, f32x4 acc[4][4],
                                       int wave, int m, int qq) {
    #pragma unroll
    for (int a = 0; a < 4; ++a)
        #pragma unroll
        for (int q = 0; q < 4; ++q) {
            const int col = q * 16 + m;
            const int rowb = wave * 64 + a * 16 + qq * 4;
            const ushort2 p01 = f2bf2(acc[a][q][0], acc[a][q][1]);
            const ushort2 p23 = f2bf2(acc[a][q][2], acc[a][q][3]);
            ushort4 w4; w4.x = p01.x; w4.y = p01.y; w4.z = p23.x; w4.w = p23.y;
            *(ushort4*)&L[col * 256 + (rowb ^ ((col & 7) << 3))] = w4;
        }
}

__global__ __launch_bounds__(256, 2) void mono(
        const float* __restrict__ x,
        const float* __restrict__ Wq, const float* __restrict__ bq,
        const float* __restrict__ gq, const float* __restrict__ betaq,
        const float* __restrict__ Wk, const float* __restrict__ bk,
        const float* __restrict__ gk, const float* __restrict__ betak,
        const float* __restrict__ Wv, const float* __restrict__ bv,
        const float* __restrict__ gv, const float* __restrict__ betav,
        float* __restrict__ out,
        float* __restrict__ Gfp, float* __restrict__ Acc,
        float* __restrict__ Sp, float* __restrict__ S,
        float* __restrict__ Ghat, float* __restrict__ xbar,
        float* __restrict__ Wp, float* __restrict__ WkTf, float* __restrict__ WvTf,
        float* __restrict__ cvec, float* __restrict__ offv,
        ushort* __restrict__ Gbf, ushort* __restrict__ WqT, ushort* __restrict__ WkT,
        ushort* __restrict__ Wvb, ushort* __restrict__ ZT, ushort* __restrict__ Tbf,
        unsigned* __restrict__ cnt) {
    __shared__ SmemU sm;
    const int blk = blockIdx.x, tid = threadIdx.x;
    const unsigned NB = gridDim.x;
    unsigned* fcnt = cnt;
    unsigned* fep  = cnt + 32;
    unsigned* mcnt = cnt + 64;
    unsigned* mep  = cnt + 96;

    // ================= Phase 0: gram -> atomic fp32 G =================
    if (blk < 192) {
        const int ks = blk & 7, b = (blk >> 3) & 7, tt = blk >> 6;
        const int it = (tt == 1) ? 1 : 0;
        const int jt = (tt == 0) ? 0 : 1;
        const bool diag = (tt < 2);
        const int i0 = it * 128, j0 = jt * 128, k0 = ks * 512;
        const float* xb = x + (long)b * CC * NPIX;
        const int c = tid & 15, rp = tid >> 4;
        const int wave = tid >> 6, lane = tid & 63;
        const int wr = (wave >> 1) * 64, wc = (wave & 1) * 64;
        const int m = lane & 15, q8 = (lane >> 4) * 8;

        if (tid < 128) sm.g.rs[tid] = 0.f;
        float rloc[8] = {};
        f32x4 acc[4][4];
        #pragma unroll
        for (int a = 0; a < 4; ++a)
            #pragma unroll
            for (int q = 0; q < 4; ++q) acc[a][q] = (f32x4){0.f, 0.f, 0.f, 0.f};

        const float* Abase = xb + (long)i0 * NPIX + k0 + c * 4;
        const float* Bbase = xb + (long)j0 * NPIX + k0 + c * 4;

        float4 va[8], vb[8];
        #pragma unroll
        for (int pp = 0; pp < 8; ++pp)
            va[pp] = *(const float4*)&Abase[(long)(pp * 16 + rp) * NPIX];
        if (!diag) {
            #pragma unroll
            for (int pp = 0; pp < 8; ++pp)
                vb[pp] = *(const float4*)&Bbase[(long)(pp * 16 + rp) * NPIX];
        }

        for (int kc = 0; kc < 512; kc += 64) {
            __syncthreads();
            #pragma unroll
            for (int pp = 0; pp < 8; ++pp) {
                const int row = pp * 16 + rp;
                const float4 v = va[pp];
                rloc[pp] += v.x + v.y + v.z + v.w;
                const ushort2 w01 = f2bf2(v.x, v.y);
                const ushort2 w23 = f2bf2(v.z, v.w);
                ushort4 w; w.x = w01.x; w.y = w01.y; w.z = w23.x; w.w = w23.y;
                *(ushort4*)&sm.g.Ab[row * 72 + c * 4] = w;
            }
            if (!diag) {
                #pragma unroll
                for (int pp = 0; pp < 8; ++pp) {
                    const int row = pp * 16 + rp;
                    const float4 v = vb[pp];
                    const ushort2 w01 = f2bf2(v.x, v.y);
                    const ushort2 w23 = f2bf2(v.z, v.w);
                    ushort4 w; w.x = w01.x; w.y = w01.y; w.z = w23.x; w.w = w23.y;
                    *(ushort4*)&sm.g.Bb[row * 72 + c * 4] = w;
                }
            }
            const int kn = kc + 64;
            if (kn < 512) {
                #pragma unroll
                for (int pp = 0; pp < 8; ++pp)
                    va[pp] = *(const float4*)&Abase[(long)(pp * 16 + rp) * NPIX + kn];
                if (!diag) {
                    #pragma unroll
                    for (int pp = 0; pp < 8; ++pp)
                        vb[pp] = *(const float4*)&Bbase[(long)(pp * 16 + rp) * NPIX + kn];
                }
            }
            __syncthreads();
            const ushort* Bsrc = diag ? sm.g.Ab : sm.g.Bb;
            #pragma unroll
            for (int kk = 0; kk < 2; ++kk) {
                short8 af[4], bfv[4];
                #pragma unroll
                for (int a = 0; a < 4; ++a)
                    af[a] = *(const short8*)&sm.g.Ab[(wr + a * 16 + m) * 72 + kk * 32 + q8];
                #pragma unroll
                for (int q = 0; q < 4; ++q)
                    bfv[q] = *(const short8*)&Bsrc[(wc + q * 16 + m) * 72 + kk * 32 + q8];
                #pragma unroll
                for (int a = 0; a < 4; ++a)
                    #pragma unroll
                    for (int q = 0; q < 4; ++q)
                        acc[a][q] = MFMA16(af[a], bfv[q], acc[a][q]);
            }
        }
        if (diag) {
            #pragma unroll
            for (int pp = 0; pp < 8; ++pp) atomicAdd(&sm.g.rs[pp * 16 + rp], rloc[pp]);
            __syncthreads();
            if (tid < 128) Sp[(((long)ks * 8 + b) * 2 + it) * 128 + tid] = sm.g.rs[tid];
        }
        // accumulate the partial tile straight into fp32 G (zeroed by memset)
        float* Gt = Gfp + (long)(b * 3 + tt) * 16384;
        const int rq = (lane >> 4) * 4;
        #pragma unroll
        for (int a = 0; a < 4; ++a) {
            #pragma unroll
            for (int q = 0; q < 4; ++q) {
                const int col = wc + q * 16 + m;
                #pragma unroll
                for (int reg = 0; reg < 4; ++reg)
                    atomicAdd(&Gt[(wr + a * 16 + rq + reg) * 128 + col], acc[a][q][reg]);
            }
        }
    }
    gbar(fcnt, fep, 1, NB);

    // ============ Phase A: Gfp -> Gbf (mirrored), Ghat ; S/xbar ============
    if (blk < 48) {
        const int tt = blk >> 4, sub = blk & 15;
        const int sr = (sub >> 2) * 32, sc = (sub & 3) * 32;
        const int it = (tt == 1) ? 1 : 0;
        const int jt = (tt == 0) ? 0 : 1;
        const bool offd = (tt == 2);
        const int gi0 = it * 128 + sr, gj0 = jt * 128 + sc;
        const int r = tid >> 3, c4 = (tid & 7) * 4;
        const float inv = 1.0f / PTOT;
        float g0 = 0.f, g1 = 0.f, g2 = 0.f, g3 = 0.f;
        for (int b = 0; b < BB; ++b) {
            const float4 v = *(const float4*)&Gfp[(long)(b * 3 + tt) * 16384
                                                  + (long)(sr + r) * 128 + sc + c4];
            ushort4 w;
            w.x = f2bf(v.x); w.y = f2bf(v.y); w.z = f2bf(v.z); w.w = f2bf(v.w);
            *(ushort4*)&Gbf[(long)b * 65536 + (long)(gi0 + r) * 256 + gj0 + c4] = w;
            g0 += v.x; g1 += v.y; g2 += v.z; g3 += v.w;
            if (offd) {
                sm.rm.tile[r][c4 + 0] = v.x; sm.rm.tile[r][c4 + 1] = v.y;
                sm.rm.tile[r][c4 + 2] = v.z; sm.rm.tile[r][c4 + 3] = v.w;
                __syncthreads();
                ushort4 tw;
                tw.x = f2bf(sm.rm.tile[c4 + 0][r]); tw.y = f2bf(sm.rm.tile[c4 + 1][r]);
                tw.z = f2bf(sm.rm.tile[c4 + 2][r]); tw.w = f2bf(sm.rm.tile[c4 + 3][r]);
                *(ushort4*)&Gbf[(long)b * 65536 + (long)(gj0 + r) * 256 + gi0 + c4] = tw;
                __syncthreads();
            }
        }
        float4 gh;
        gh.x = g0 * inv; gh.y = g1 * inv; gh.z = g2 * inv; gh.w = g3 * inv;
        *(float4*)&Ghat[(long)(gi0 + r) * 256 + gj0 + c4] = gh;
        if (offd) {
            sm.rm.tile[r][c4 + 0] = gh.x; sm.rm.tile[r][c4 + 1] = gh.y;
            sm.rm.tile[r][c4 + 2] = gh.z; sm.rm.tile[r][c4 + 3] = gh.w;
            __syncthreads();
            float4 t4;
            t4.x = sm.rm.tile[c4 + 0][r]; t4.y = sm.rm.tile[c4 + 1][r];
            t4.z = sm.rm.tile[c4 + 2][r]; t4.w = sm.rm.tile[c4 + 3][r];
            *(float4*)&Ghat[(long)(gj0 + r) * 256 + gi0 + c4] = t4;
        }
    } else if (blk == 48) {
        const int it2 = tid >> 7, rr = tid & 127;
        float xacc = 0.f;
        for (int b = 0; b < BB; ++b) {
            float acc = 0.f;
            #pragma unroll
            for (int ks = 0; ks < 8; ++ks)
                acc += Sp[(((long)ks * 8 + b) * 2 + it2) * 128 + rr];
            S[b * 256 + tid] = acc;
            xacc += acc;
        }
        xbar[tid] = xacc * (1.0f / PTOT);
    }
    gbar(fcnt, fep, 2, NB);

    // ================= Phase B: BN stats + Acc zeroing =================
    if (blk < 192) {
        const int og = blk & 63, t = blk >> 6;
        const int o0 = og * 4;
        const float* Wt  = t == 0 ? Wq : (t == 1 ? Wk : Wv);
        const float* bt  = t == 0 ? bq : (t == 1 ? bk : bv);
        const float* gt  = t == 0 ? gq : (t == 1 ? gk : gv);
        const float* bet = t == 0 ? betaq : (t == 1 ? betak : betav);
        #pragma unroll
        for (int i = 0; i < 4; ++i) sm.st.wr4[i][tid] = Wt[(o0 + i) * 256 + tid];
        const float xb = xbar[tid];
        __syncthreads();
        const float* grow = Ghat + (long)tid * 256;
        float tj[4] = {0.f, 0.f, 0.f, 0.f};
        #pragma unroll 8
        for (int k = 0; k < 256; k += 4) {
            const float4 g = *(const float4*)&grow[k];
            #pragma unroll
            for (int i = 0; i < 4; ++i)
                tj[i] += g.x * sm.st.wr4[i][k]     + g.y * sm.st.wr4[i][k + 1]
                       + g.z * sm.st.wr4[i][k + 2] + g.w * sm.st.wr4[i][k + 3];
        }
        #pragma unroll
        for (int i = 0; i < 4; ++i) {
            const int o = o0 + i;
            const float wv = sm.st.wr4[i][tid];
            const float2 qw = wred2(wv * tj[i], wv * xb, sm.st.red8, tid);
            const float bo = bt[o];
            const float mu = qw.y + bo;
            const float var = qw.x + 2.f * bo * mu - bo * bo - mu * mu;
            const float a = gt[o] * rsqrtf(var + EPSV);
            const float wpv = a * wv;
            Wp[(long)t * 65536 + o * 256 + tid] = wpv;
            const ushort wb = f2bf(wpv);
            if (t == 0) {
                WqT[(long)tid * 256 + o] = wb;
            } else if (t == 1) {
                WkT[(long)tid * 256 + o] = wb;
                WkTf[(long)tid * 256 + o] = wpv;
            } else {
                Wvb[(long)o * 256 + tid] = wb;
                WvTf[(long)tid * 256 + o] = wpv;
            }
            if (tid == 0) cvec[t * 256 + o] = a * (bo - mu) + bet[o];
        }
    } else if (blk < 226) {
        const int idx = (blk - 192) * 256 + tid;
        if (idx < ACC_N) Acc[idx] = 0.f;
    }
    gbar(fcnt, fep, 3, NB);

    // ======= Phases C1..C3 + D: only blocks 0..39, mini-barriers =======
    if (blk < 40) {
        // ---- C1: partial u,w (0-31); partial y,r (32-35); Z GEMM (36-39)
        if (blk < 32) {
            const int b = blk >> 2, i0b = (blk & 3) * 64;
            if (tid < 64) sm.vx.sh[tid] = S[b * 256 + i0b + tid];
            __syncthreads();
            float uu = 0.f, ww = 0.f;
            #pragma unroll 8
            for (int i = 0; i < 64; ++i) {
                const float sv = sm.vx.sh[i];
                uu += WvTf[(long)(i0b + i) * 256 + tid] * sv;
                ww += WkTf[(long)(i0b + i) * 256 + tid] * sv;
            }
            atomicAdd(&Acc[ACC_U + b * 256 + tid], uu);
            atomicAdd(&Acc[ACC_W + b * 256 + tid], ww);
        } else if (blk < 36) {
            const int o0 = (blk - 32) * 64;
            if (tid < 64) {
                sm.vx.cqs[tid] = cvec[o0 + tid];
                sm.vx.cks[tid] = cvec[256 + o0 + tid];
            }
            __syncthreads();
            float yy = 0.f, rr = 0.f;
            #pragma unroll 8
            for (int i = 0; i < 64; ++i) {
                yy += Wp[65536L + (long)(o0 + i) * 256 + tid] * sm.vx.cqs[i];
                rr += Wp[(long)(o0 + i) * 256 + tid] * sm.vx.cks[i];
            }
            atomicAdd(&Acc[ACC_Y + tid], yy);
            atomicAdd(&Acc[ACC_R + tid], rr);
        } else {
            // Z GEMM slice (computed ONCE, shared by all b in D)
            const int j0 = (blk - 36) * 64;
            const int wave = tid >> 6, lane = tid & 63;
            const int m = lane & 15, qq = lane >> 4;
            f32x4 acc[4][4];
            #pragma unroll
            for (int a = 0; a < 4; ++a)
                #pragma unroll
                for (int q = 0; q < 4; ++q) acc[a][q] = (f32x4){0.f, 0.f, 0.f, 0.f};
            mm256x64(acc, WkT, WqT + (long)j0 * 256, nullptr, wave, m, qq);
            #pragma unroll
            for (int a = 0; a < 4; ++a)
                #pragma unroll
                for (int q = 0; q < 4; ++q) {
                    const int col = j0 + q * 16 + m;
                    const int rowb = wave * 64 + a * 16 + qq * 4;
                    const ushort2 p01 = f2bf2(acc[a][q][0], acc[a][q][1]);
                    const ushort2 p23 = f2bf2(acc[a][q][2], acc[a][q][3]);
                    ushort4 w4; w4.x = p01.x; w4.y = p01.y; w4.z = p23.x; w4.w = p23.y;
                    *(ushort4*)&ZT[(long)col * 256 + rowb] = w4;
                }
        }
        gbar(mcnt, mep, 1, 40);

        // ---- C2: partial h, g (0-31)
        if (blk < 32) {
            const int b = blk >> 2, o0 = (blk & 3) * 64;
            if (tid < 64) {
                sm.vx.wl[tid] = Acc[ACC_W + b * 256 + o0 + tid];
                sm.vx.yl[tid] = Acc[ACC_Y + o0 + tid];
            }
            __syncthreads();
            float hh = 0.f, gg = 0.f;
            #pragma unroll 8
            for (int i = 0; i < 64; ++i) {
                hh += Wp[(long)(o0 + i) * 256 + tid] * sm.vx.wl[i];
                gg += bf2f(Gbf[(long)b * 65536 + (long)(o0 + i) * 256 + tid]) * sm.vx.yl[i];
            }
            atomicAdd(&Acc[ACC_H + b * 256 + tid], hh);
            atomicAdd(&Acc[ACC_G + b * 256 + tid], gg);
        }
        gbar(mcnt, mep, 2, 40);

        // ---- C3: vg + scalars -> offv (0-7)
        if (blk < 8) {
            const int b = blk;
            sm.vx.cqs[tid] = cvec[tid];
            sm.vx.cks[tid] = cvec[256 + tid];
            sm.vx.wl[tid]  = Acc[ACC_W + b * 256 + tid];
            sm.vx.gyl[tid] = Acc[ACC_G + b * 256 + tid];
            __syncthreads();
            float vg = 0.f;
            #pragma unroll 8
            for (int j = 0; j < 256; ++j) vg += WvTf[(long)j * 256 + tid] * sm.vx.gyl[j];
            const float cv = cvec[512 + tid];
            const float uu = Acc[ACC_U + b * 256 + tid];
            const float dkq = block_reduce(sm.vx.cqs[tid] * sm.vx.cks[tid], sm.vx.red, tid);
            const float dwq = block_reduce(sm.vx.wl[tid] * sm.vx.cqs[tid], sm.vx.red, tid);
            offv[b * 256 + tid] = SCALEV * (vg + uu * dkq + cv * (dwq + 4096.0f * dkq));
        }
        gbar(mcnt, mep, 3, 40);

        // ---- D: F = G Z (Z from global) -> LDS ; T = Wv' F + epilogue
        if (blk < 32) {
            const int b = blk >> 2, j0 = (blk & 3) * 64;
            const int wave = tid >> 6, lane = tid & 63;
            const int m = lane & 15, qq = lane >> 4;
            f32x4 acc[4][4];
            #pragma unroll
            for (int a = 0; a < 4; ++a)
                #pragma unroll
                for (int q = 0; q < 4; ++q) acc[a][q] = (f32x4){0.f, 0.f, 0.f, 0.f};
            mm256x64(acc, Gbf + (long)b * 65536, ZT + (long)j0 * 256, nullptr, wave, m, qq);
            st_lds(sm.ch.zt, acc, wave, m, qq);
            __syncthreads();
            #pragma unroll
            for (int a = 0; a < 4; ++a)
                #pragma unroll
                for (int q = 0; q < 4; ++q) acc[a][q] = (f32x4){0.f, 0.f, 0.f, 0.f};
            mm256x64(acc, Wvb, nullptr, sm.ch.zt, wave, m, qq);
            const int rq4 = qq * 4;
            #pragma unroll
            for (int a = 0; a < 4; ++a) {
                #pragma unroll
                for (int q = 0; q < 4; ++q) {
                    const int cg = j0 + q * 16 + m;
                    const float rv = Acc[ACC_R + cg];
                    const float t2 = Acc[ACC_H + b * 256 + cg] + 4096.0f * rv;
                    #pragma unroll
                    for (int reg = 0; reg < 4; ++reg) {
                        const int row = wave * 64 + a * 16 + rq4 + reg;
                        const float val = SCALEV * (acc[a][q][reg]
                                                    + Acc[ACC_U + b * 256 + row] * rv
                                                    + cvec[512 + row] * t2);
                        Tbf[(long)b * 65536 + (long)row * 256 + cg] = f2bf(val);
                    }
                }
            }
        }
    }
    gbar(fcnt, fep, 4, NB);

    // ================= Phase E: out = T x + off (2 tiles/block) ================
    for (int v = blk; v < 512; v += 256) {
        const int p0 = (v & 63) * 64;
        const int b = v >> 6;
        const float* xb = x + (long)b * CC * NPIX;
        const ushort* Tb = Tbf + (long)b * 65536;
        __syncthreads();

        const int c = tid & 15, kq = tid >> 4;
        #pragma unroll
        for (int kt = 0; kt < 4; ++kt) {
            const int k4 = kt * 64 + kq * 4;
            const int p = c * 4;
            const float4 v0 = *(const float4*)&xb[(long)(k4 + 0) * NPIX + p0 + p];
            const float4 v1 = *(const float4*)&xb[(long)(k4 + 1) * NPIX + p0 + p];
            const float4 v2 = *(const float4*)&xb[(long)(k4 + 2) * NPIX + p0 + p];
            const float4 v3 = *(const float4*)&xb[(long)(k4 + 3) * NPIX + p0 + p];
            ushort2 a01, a23;
            ushort4 w;
            a01 = f2bf2(v0.x, v1.x); a23 = f2bf2(v2.x, v3.x);
            w.x = a01.x; w.y = a01.y; w.z = a23.x; w.w = a23.y;
            *(ushort4*)&sm.op.Bs[(p + 0) * 264 + k4] = w;
            a01 = f2bf2(v0.y, v1.y); a23 = f2bf2(v2.y, v3.y);
            w.x = a01.x; w.y = a01.y; w.z = a23.x; w.w = a23.y;
            *(ushort4*)&sm.op.Bs[(p + 1) * 264 + k4] = w;
            a01 = f2bf2(v0.z, v1.z); a23 = f2bf2(v2.z, v3.z);
            w.x = a01.x; w.y = a01.y; w.z = a23.x; w.w = a23.y;
            *(ushort4*)&sm.op.Bs[(p + 2) * 264 + k4] = w;
            a01 = f2bf2(v0.w, v1.w); a23 = f2bf2(v2.w, v3.w);
            w.x = a01.x; w.y = a01.y; w.z = a23.x; w.w = a23.y;
            *(ushort4*)&sm.op.Bs[(p + 3) * 264 + k4] = w;
        }
        __syncthreads();

        const int wave = tid >> 6, lane = tid & 63;
        const int wr = wave * 64;
        const int m = lane & 15, q8 = (lane >> 4) * 8;
        f32x4 acc[4][4];
        #pragma unroll
        for (int a = 0; a < 4; ++a)
            #pragma unroll
            for (int q = 0; q < 4; ++q) acc[a][q] = (f32x4){0.f, 0.f, 0.f, 0.f};

        #pragma unroll
        for (int kk = 0; kk < 8; ++kk) {
            short8 af[4], bfv[4];
            #pragma unroll
            for (int a = 0; a < 4; ++a)
                af[a] = *(const short8*)&Tb[(long)(wr + a * 16 + m) * 256 + kk * 32 + q8];
            #pragma unroll
            for (int q = 0; q < 4; ++q)
                bfv[q] = *(const short8*)&sm.op.Bs[(q * 16 + m) * 264 + kk * 32 + q8];
            #pragma unroll
            for (int a = 0; a < 4; ++a)
                #pragma unroll
                for (int q = 0; q < 4; ++q)
                    acc[a][q] = MFMA16(af[a], bfv[q], acc[a][q]);
        }

        const int rq = (lane >> 4) * 4;
        #pragma unroll
        for (int a = 0; a < 4; ++a) {
            #pragma unroll
            for (int reg = 0; reg < 4; ++reg) {
                const int row = wr + a * 16 + rq + reg;
                const float off_ = offv[b * CC + row];
                float* orow = &out[((long)b * CC + row) * NPIX + p0];
                #pragma unroll
                for (int q = 0; q < 4; ++q)
                    orow[q * 16 + m] = acc[a][q][reg] + off_;
            }
        }
    }
}

extern "C" void kernel_launch(void* const* d_in, const int* in_sizes, int n_in,
                              void* d_out, int out_size, void* d_ws, size_t ws_size,
                              hipStream_t stream) {
    const float* x     = (const float*)d_in[0];
    const float* Wq    = (const float*)d_in[1];
    const float* bq    = (const float*)d_in[2];
    const float* gq    = (const float*)d_in[3];
    const float* betaq = (const float*)d_in[4];
    const float* Wk    = (const float*)d_in[5];
    const float* bk    = (const float*)d_in[6];
    const float* gk    = (const float*)d_in[7];
    const float* betak = (const float*)d_in[8];
    const float* Wv    = (const float*)d_in[9];
    const float* bv    = (const float*)d_in[10];
    const float* gv    = (const float*)d_in[11];
    const float* betav = (const float*)d_in[12];
    float* ws = (float*)d_ws;

    float*  Gfp  = ws + OFF_GFP;
    float*  Acc  = ws + OFF_ACC;
    float*  Sp   = ws + OFF_SP;
    float*  S    = ws + OFF_S;
    float*  Ghat = ws + OFF_GHAT;
    float*  Xbar = ws + OFF_XBAR;
    float*  Wp   = ws + OFF_WP;
    float*  WkTf = ws + OFF_WKTF;
    float*  WvTf = ws + OFF_WVTF;
    float*  cvec = ws + OFF_CVEC;
    float*  OffV = ws + OFF_OFFV;
    ushort* Gbf  = (ushort*)(ws + OFF_GBF);
    ushort* WqT  = (ushort*)(ws + OFF_WQT);
    ushort* WkT  = (ushort*)(ws + OFF_WKT);
    ushort* Wvb  = (ushort*)(ws + OFF_WVB);
    ushort* ZT   = (ushort*)(ws + OFF_ZT);
    ushort* Tbf  = (ushort*)(ws + OFF_TBF);
    unsigned* Cnt = (unsigned*)(ws + OFF_CNT);

    hipMemsetAsync((void*)Gfp, 0, 393216 * sizeof(float), stream);
    hipMemsetAsync((void*)Cnt, 0, 512, stream);
    mono<<<256, 256, 0, stream>>>(x, Wq, bq, gq, betaq, Wk, bk, gk, betak,
                                  Wv, bv, gv, betav, (float*)d_out,
                                  Gfp, Acc, Sp, S, Ghat, Xbar, Wp, WkTf, WvTf,
                                  cvec, OffV, Gbf, WqT, WkT, Wvb, ZT, Tbf, Cnt);
}

// Round 7
// 217.431 us; speedup vs baseline: 2.1811x; 2.0524x over previous
//
#include <hip/hip_runtime.h>
#include <hip/hip_bf16.h>

// PatchAttentionLayer R13: revert to dispatch structure (R8 lineage), 6 dispatches.
//   gram: ks=16 (384 blocks, 4 kc-chunks) -> Pg partials; zeroes Ghat; rowsums.
//   reduce_mirror: 385 blocks, 16-deep ks sum -> Gbf (mirrored), Ghat(atomic), S, xbar.
//   stats_quad: grid (64,3), 4 outs/block -> Wp, transposes, cvec.
//   zmidabc: {Z GEMM (4 blocks) | per-batch full matvec chain (8 blocks):
//             u,w,y,r,h,g,vg -> u, hb, r, offv}.  [was zmida+bcF-mid]
//   gemm_FT: per (b, 64-col slice): F = G_b Z -> LDS (swizzled), T = Wv' F +
//            rank-1 epilogue -> Tbf. 32 blocks.   [was bcF-F + gemm_T, no FT buf]
//   out_mfma: out_b = T_b x_b + off (64-pixel tiles, 512 blocks).
// No global-atomic hot spots (Ghat atomics are 1-shot per element, R8-proven).

#define BB 8
#define CC 256
#define NPIX 4096
#define PTOT 32768
#define EPSV 1e-5f
#define SCALEV 0.125f

// ---- workspace layout (float offsets) ----
#define OFF_PG    0L          // 384*16384 = 6291456 (gram partials, ks=16)
#define OFF_SP    6291456L    // 32768 (rowsum partials)
#define OFF_S     6324224L    // 2048
#define OFF_GHAT  6326272L    // 65536
#define OFF_XBAR  6391808L    // 256
#define OFF_WP    6392064L    // 196608
#define OFF_WKTF  6588672L    // 65536
#define OFF_WVTF  6654208L    // 65536
#define OFF_CVEC  6719744L    // 768
#define OFF_U     6720512L    // 2048
#define OFF_HB    6722560L    // 2048
#define OFF_R     6724608L    // 256
#define OFF_OFFV  6724864L    // 2048
#define OFF_GBF   6726912L    // 8*65536 ushort = 262144 floats
#define OFF_WQT   6989056L    // 32768
#define OFF_WKT   7021824L    // 32768
#define OFF_WVB   7054592L    // 32768
#define OFF_ZT    7087360L    // 32768
#define OFF_TBF   7120128L    // 262144
// total 7382272 floats = 29.5 MB

typedef __attribute__((ext_vector_type(8))) short short8;
typedef __attribute__((ext_vector_type(4))) float f32x4;

#define MFMA16(a, b, c) __builtin_amdgcn_mfma_f32_16x16x32_bf16((a), (b), (c), 0, 0, 0)

__device__ __forceinline__ ushort f2bf(float f) {
    union { float f; unsigned u; } v; v.f = f;
    const unsigned r = (v.u + 0x7FFFu + ((v.u >> 16) & 1u)) >> 16;
    return (ushort)r;
}

__device__ __forceinline__ float bf2f(ushort u) {
    union { unsigned u; float f; } v; v.u = ((unsigned)u) << 16;
    return v.f;
}

// packed RNE f32x2 -> bf16x2 (v_cvt_pk_bf16_f32 on gfx950)
__device__ __forceinline__ ushort2 f2bf2(float a, float b) {
    __hip_bfloat162 h = __float22bfloat162_rn(float2{a, b});
    union { __hip_bfloat162 h; ushort2 u; } v; v.h = h;
    return v.u;
}

__device__ __forceinline__ float block_reduce(float v, float* red, int tid) {
    red[tid] = v; __syncthreads();
    for (int st = 128; st > 0; st >>= 1) {
        if (tid < st) red[tid] += red[tid + st];
        __syncthreads();
    }
    float r = red[0]; __syncthreads();
    return r;
}

// dual wave-shuffle block reduction (sum of a and b over 256 threads)
__device__ __forceinline__ float2 wred2(float a, float b, float* red8, int tid) {
    #pragma unroll
    for (int s = 32; s > 0; s >>= 1) {
        a += __shfl_xor(a, s);
        b += __shfl_xor(b, s);
    }
    if ((tid & 63) == 0) { red8[(tid >> 6) * 2] = a; red8[(tid >> 6) * 2 + 1] = b; }
    __syncthreads();
    const float ra = red8[0] + red8[2] + red8[4] + red8[6];
    const float rb = red8[1] + red8[3] + red8[5] + red8[7];
    __syncthreads();
    return float2{ra, rb};
}

// ---- Gram via MFMA: 128x128 upper tiles, ks=16 (R13), partial stores ----
// grid (16 ks, 8 b, 3 tt): tt=0 -> (0,0); tt=1 -> (1,1); tt=2 -> (0,1)
__global__ __launch_bounds__(256, 2) void gram_mfma(const float* __restrict__ x,
                                                    float* __restrict__ Pg,
                                                    float* __restrict__ Sp,
                                                    float* __restrict__ Ghat) {
    __shared__ __align__(16) ushort Ab[128 * 72];
    __shared__ __align__(16) ushort Bb[128 * 72];
    __shared__ float rs[128];
    const int tid = threadIdx.x;
    const int ks = blockIdx.x, b = blockIdx.y, tt = blockIdx.z;
    const int lb = (tt * 8 + b) * 16 + ks;
    if (lb < 64) {
        #pragma unroll
        for (int i = 0; i < 4; ++i) Ghat[lb * 1024 + i * 256 + tid] = 0.f;
    }
    const int it = (tt == 1) ? 1 : 0;
    const int jt = (tt == 0) ? 0 : 1;
    const bool diag = (tt < 2);
    const int i0 = it * 128, j0 = jt * 128, k0 = ks * 256;
    const float* xb = x + (long)b * CC * NPIX;
    const int c = tid & 15, rp = tid >> 4;
    const int wave = tid >> 6, lane = tid & 63;
    const int wr = (wave >> 1) * 64, wc = (wave & 1) * 64;
    const int m = lane & 15, q8 = (lane >> 4) * 8;

    if (tid < 128) rs[tid] = 0.f;
    float rloc[8] = {};
    f32x4 acc[4][4];
    #pragma unroll
    for (int a = 0; a < 4; ++a)
        #pragma unroll
        for (int q = 0; q < 4; ++q) acc[a][q] = (f32x4){0.f, 0.f, 0.f, 0.f};

    const float* Abase = xb + (long)i0 * NPIX + k0 + c * 4;
    const float* Bbase = xb + (long)j0 * NPIX + k0 + c * 4;

    // prefetch kc=0 into registers
    float4 va[8], vb[8];
    #pragma unroll
    for (int pp = 0; pp < 8; ++pp)
        va[pp] = *(const float4*)&Abase[(long)(pp * 16 + rp) * NPIX];
    if (!diag) {
        #pragma unroll
        for (int pp = 0; pp < 8; ++pp)
            vb[pp] = *(const float4*)&Bbase[(long)(pp * 16 + rp) * NPIX];
    }

    for (int kc = 0; kc < 256; kc += 64) {
        __syncthreads();
        #pragma unroll
        for (int pp = 0; pp < 8; ++pp) {
            const int row = pp * 16 + rp;
            const float4 v = va[pp];
            rloc[pp] += v.x + v.y + v.z + v.w;
            const ushort2 w01 = f2bf2(v.x, v.y);
            const ushort2 w23 = f2bf2(v.z, v.w);
            ushort4 w; w.x = w01.x; w.y = w01.y; w.z = w23.x; w.w = w23.y;
            *(ushort4*)&Ab[row * 72 + c * 4] = w;
        }
        if (!diag) {
            #pragma unroll
            for (int pp = 0; pp < 8; ++pp) {
                const int row = pp * 16 + rp;
                const float4 v = vb[pp];
                const ushort2 w01 = f2bf2(v.x, v.y);
                const ushort2 w23 = f2bf2(v.z, v.w);
                ushort4 w; w.x = w01.x; w.y = w01.y; w.z = w23.x; w.w = w23.y;
                *(ushort4*)&Bb[row * 72 + c * 4] = w;
            }
        }
        const int kn = kc + 64;
        if (kn < 256) {
            #pragma unroll
            for (int pp = 0; pp < 8; ++pp)
                va[pp] = *(const float4*)&Abase[(long)(pp * 16 + rp) * NPIX + kn];
            if (!diag) {
                #pragma unroll
                for (int pp = 0; pp < 8; ++pp)
                    vb[pp] = *(const float4*)&Bbase[(long)(pp * 16 + rp) * NPIX + kn];
            }
        }
        __syncthreads();
        const ushort* Bsrc = diag ? Ab : Bb;
        #pragma unroll
        for (int kk = 0; kk < 2; ++kk) {
            short8 af[4], bfv[4];
            #pragma unroll
            for (int a = 0; a < 4; ++a)
                af[a] = *(const short8*)&Ab[(wr + a * 16 + m) * 72 + kk * 32 + q8];
            #pragma unroll
            for (int q = 0; q < 4; ++q)
                bfv[q] = *(const short8*)&Bsrc[(wc + q * 16 + m) * 72 + kk * 32 + q8];
            #pragma unroll
            for (int a = 0; a < 4; ++a)
                #pragma unroll
                for (int q = 0; q < 4; ++q)
                    acc[a][q] = MFMA16(af[a], bfv[q], acc[a][q]);
        }
    }
    if (diag) {
        #pragma unroll
        for (int pp = 0; pp < 8; ++pp) atomicAdd(&rs[pp * 16 + rp], rloc[pp]);
        __syncthreads();
        if (tid < 128) Sp[(((long)ks * 8 + b) * 2 + it) * 128 + tid] = rs[tid];
    }
    float* Pt = Pg + (((long)ks * 8 + b) * 3 + tt) * 16384;
    const int rq = (lane >> 4) * 4;
    #pragma unroll
    for (int a = 0; a < 4; ++a) {
        #pragma unroll
        for (int q = 0; q < 4; ++q) {
            const int col = wc + q * 16 + m;
            #pragma unroll
            for (int reg = 0; reg < 4; ++reg)
                Pt[(long)(wr + a * 16 + rq + reg) * 128 + col] = acc[a][q][reg];
        }
    }
}

// ---- reduce partials -> Gbf (full, mirrored), Ghat (atomic); S; xbar ----
// grid 385. blk<384: (tt = blk>>7, sub = (blk>>3)&15, b = blk&7), 16-deep ks sum.
__global__ __launch_bounds__(256) void reduce_mirror(const float* __restrict__ Pg,
                                                     const float* __restrict__ Sp,
                                                     ushort* __restrict__ Gbf,
                                                     float* __restrict__ Ghat,
                                                     float* __restrict__ S,
                                                     float* __restrict__ xbar) {
    const int blk = blockIdx.x, tid = threadIdx.x;
    if (blk == 384) {
        const int it2 = tid >> 7, rr = tid & 127;
        float xacc = 0.f;
        for (int b = 0; b < BB; ++b) {
            float acc = 0.f;
            #pragma unroll
            for (int ks = 0; ks < 16; ++ks)
                acc += Sp[(((long)ks * 8 + b) * 2 + it2) * 128 + rr];
            S[b * 256 + tid] = acc;
            xacc += acc;
        }
        xbar[tid] = xacc * (1.0f / PTOT);
        return;
    }
    __shared__ float tile[32][33];
    const int tt = blk >> 7;
    const int sub = (blk >> 3) & 15;
    const int b = blk & 7;
    const int sr = (sub >> 2) * 32, sc = (sub & 3) * 32;
    const int it = (tt == 1) ? 1 : 0;
    const int jt = (tt == 0) ? 0 : 1;
    const bool offd = (tt == 2);
    const int gi0 = it * 128 + sr, gj0 = jt * 128 + sc;
    const int r = tid >> 3, c4 = (tid & 7) * 4;
    const float inv = 1.0f / PTOT;

    float s0 = 0.f, s1 = 0.f, s2 = 0.f, s3 = 0.f;
    #pragma unroll
    for (int ks = 0; ks < 16; ++ks) {
        const float4 v = *(const float4*)&Pg[(((long)ks * 8 + b) * 3 + tt) * 16384
                                             + (long)(sr + r) * 128 + sc + c4];
        s0 += v.x; s1 += v.y; s2 += v.z; s3 += v.w;
    }
    ushort4 w;
    w.x = f2bf(s0); w.y = f2bf(s1); w.z = f2bf(s2); w.w = f2bf(s3);
    *(ushort4*)&Gbf[(long)b * 65536 + (long)(gi0 + r) * 256 + gj0 + c4] = w;
    float* gd = &Ghat[(long)(gi0 + r) * 256 + gj0 + c4];
    atomicAdd(gd + 0, s0 * inv);
    atomicAdd(gd + 1, s1 * inv);
    atomicAdd(gd + 2, s2 * inv);
    atomicAdd(gd + 3, s3 * inv);
    if (offd) {
        tile[r][c4 + 0] = s0; tile[r][c4 + 1] = s1;
        tile[r][c4 + 2] = s2; tile[r][c4 + 3] = s3;
        __syncthreads();
        const float t0 = tile[c4 + 0][r], t1 = tile[c4 + 1][r];
        const float t2 = tile[c4 + 2][r], t3 = tile[c4 + 3][r];
        ushort4 tw;
        tw.x = f2bf(t0); tw.y = f2bf(t1); tw.z = f2bf(t2); tw.w = f2bf(t3);
        *(ushort4*)&Gbf[(long)b * 65536 + (long)(gj0 + r) * 256 + gi0 + c4] = tw;
        float* gm = &Ghat[(long)(gj0 + r) * 256 + gi0 + c4];
        atomicAdd(gm + 0, t0 * inv);
        atomicAdd(gm + 1, t1 * inv);
        atomicAdd(gm + 2, t2 * inv);
        atomicAdd(gm + 3, t3 * inv);
    }
}

// ---- BN stats; 4 output channels per block, grid (64,3) ----
__global__ __launch_bounds__(256) void stats_quad(const float* __restrict__ Wq, const float* __restrict__ Wk,
                           const float* __restrict__ Wv, const float* __restrict__ Ghat,
                           const float* __restrict__ xbar,
                           const float* bq, const float* gq, const float* betaq,
                           const float* bk, const float* gk, const float* betak,
                           const float* bv, const float* gv, const float* betav,
                           float* __restrict__ Wp, float* __restrict__ cvec,
                           ushort* __restrict__ WqT, ushort* __restrict__ WkT,
                           ushort* __restrict__ Wvb, float* __restrict__ WkTf,
                           float* __restrict__ WvTf) {
    const int og = blockIdx.x, t = blockIdx.y, tid = threadIdx.x;
    const int o0 = og * 4;
    const float* Wt  = t == 0 ? Wq : (t == 1 ? Wk : Wv);
    const float* bt  = t == 0 ? bq : (t == 1 ? bk : bv);
    const float* gt  = t == 0 ? gq : (t == 1 ? gk : gv);
    const float* bet = t == 0 ? betaq : (t == 1 ? betak : betav);
    __shared__ float wrows[4][256];
    __shared__ float red8[8];
    #pragma unroll
    for (int i = 0; i < 4; ++i) wrows[i][tid] = Wt[(o0 + i) * 256 + tid];
    const float xb = xbar[tid];
    __syncthreads();
    const float* grow = Ghat + (long)tid * 256;
    float tj[4] = {0.f, 0.f, 0.f, 0.f};
    #pragma unroll 8
    for (int k = 0; k < 256; k += 4) {
        const float4 g = *(const float4*)&grow[k];
        #pragma unroll
        for (int i = 0; i < 4; ++i)
            tj[i] += g.x * wrows[i][k]     + g.y * wrows[i][k + 1]
                   + g.z * wrows[i][k + 2] + g.w * wrows[i][k + 3];
    }
    #pragma unroll
    for (int i = 0; i < 4; ++i) {
        const int o = o0 + i;
        const float wv = wrows[i][tid];
        const float2 qw = wred2(wv * tj[i], wv * xb, red8, tid);
        const float bo = bt[o];
        const float mu = qw.y + bo;
        const float var = qw.x + 2.f * bo * mu - bo * bo - mu * mu;
        const float a = gt[o] * rsqrtf(var + EPSV);
        const float wpv = a * wv;
        Wp[(long)t * 65536 + o * 256 + tid] = wpv;
        const ushort wb = f2bf(wpv);
        if (t == 0) {
            WqT[(long)tid * 256 + o] = wb;
        } else if (t == 1) {
            WkT[(long)tid * 256 + o] = wb;
            WkTf[(long)tid * 256 + o] = wpv;
        } else {
            Wvb[(long)o * 256 + tid] = wb;
            WvTf[(long)tid * 256 + o] = wpv;
        }
        if (tid == 0) cvec[t * 256 + o] = a * (bo - mu) + bet[o];
    }
}

// ---- 128x128 MFMA tile, K=256, fragments direct from L2; mode-0 store ----
__device__ __forceinline__ void gemm_tile0(const ushort* __restrict__ Ab,
                                           const ushort* __restrict__ Bb,
                                           ushort* __restrict__ Db,
                                           int m0, int n0, int tid) {
    const int wave = tid >> 6, lane = tid & 63;
    const int wr = (wave >> 1) * 64, wc = (wave & 1) * 64;
    const int m = lane & 15, q8 = (lane >> 4) * 8;
    f32x4 acc[4][4];
    #pragma unroll
    for (int a = 0; a < 4; ++a)
        #pragma unroll
        for (int q = 0; q < 4; ++q) acc[a][q] = (f32x4){0.f, 0.f, 0.f, 0.f};
    #pragma unroll
    for (int kk = 0; kk < 8; ++kk) {
        short8 af[4], bfv[4];
        #pragma unroll
        for (int a = 0; a < 4; ++a)
            af[a] = *(const short8*)&Ab[(long)(m0 + wr + a * 16 + m) * 256 + kk * 32 + q8];
        #pragma unroll
        for (int q = 0; q < 4; ++q)
            bfv[q] = *(const short8*)&Bb[(long)(n0 + wc + q * 16 + m) * 256 + kk * 32 + q8];
        #pragma unroll
        for (int a = 0; a < 4; ++a)
            #pragma unroll
            for (int q = 0; q < 4; ++q)
                acc[a][q] = MFMA16(af[a], bfv[q], acc[a][q]);
    }
    const int rq = (lane >> 4) * 4;
    #pragma unroll
    for (int a = 0; a < 4; ++a) {
        #pragma unroll
        for (int q = 0; q < 4; ++q) {
            const int col = n0 + wc + q * 16 + m;
            #pragma unroll
            for (int reg = 0; reg < 4; ++reg)
                Db[(long)col * 256 + (m0 + wr + a * 16 + rq + reg)] = f2bf(acc[a][q][reg]);
        }
    }
}

// ---- fused: blocks 0-3 = Z GEMM tiles; blocks 4-11 = per-batch matvec chain ----
__global__ __launch_bounds__(256) void zmidabc(const ushort* __restrict__ WkT,
                                               const ushort* __restrict__ WqT,
                                               ushort* __restrict__ ZT,
                                               const float* __restrict__ Wp,
                                               const float* __restrict__ WkTf,
                                               const float* __restrict__ WvTf,
                                               const float* __restrict__ S,
                                               const float* __restrict__ cvec,
                                               const ushort* __restrict__ Gbf,
                                               float* __restrict__ u,
                                               float* __restrict__ hb,
                                               float* __restrict__ r_,
                                               float* __restrict__ offv) {
    const int blk = blockIdx.x, tid = threadIdx.x;
    if (blk < 4) {
        gemm_tile0(WkT, WqT, ZT, (blk >> 1) * 128, (blk & 1) * 128, tid);
        return;
    }
    const int b = blk - 4;
    __shared__ float sh[256], wl[256], yl[256], red[256], cqs[256], cks[256];
    sh[tid]  = S[b * 256 + tid];
    cqs[tid] = cvec[tid];
    cks[tid] = cvec[256 + tid];
    __syncthreads();
    float uu = 0.f, ww = 0.f, yy = 0.f, rr = 0.f;
    #pragma unroll 8
    for (int j = 0; j < 256; ++j) {
        const float sv = sh[j];
        uu += WvTf[(long)j * 256 + tid] * sv;
        ww += WkTf[(long)j * 256 + tid] * sv;
    }
    #pragma unroll 8
    for (int o = 0; o < 256; ++o) {
        yy += Wp[65536L + (long)o * 256 + tid] * cqs[o];
        rr += Wp[(long)o * 256 + tid] * cks[o];
    }
    u[b * 256 + tid] = uu;
    if (b == 0) r_[tid] = rr;
    wl[tid] = ww; yl[tid] = yy;
    __syncthreads();
    float hh = 0.f, gg = 0.f;
    #pragma unroll 8
    for (int o = 0; o < 256; ++o) {
        hh += Wp[(long)o * 256 + tid] * wl[o];
        gg += bf2f(Gbf[(long)b * 65536 + (long)o * 256 + tid]) * yl[o];
    }
    hb[b * 256 + tid] = hh;
    __syncthreads();
    sh[tid] = gg;   // reuse sh as gyl (all sh reads completed before prior sync)
    __syncthreads();
    float vg = 0.f;
    #pragma unroll 8
    for (int j = 0; j < 256; ++j) vg += WvTf[(long)j * 256 + tid] * sh[j];
    const float cv = cvec[512 + tid];
    const float dkq = block_reduce(cqs[tid] * cks[tid], red, tid);
    const float dwq = block_reduce(wl[tid] * cqs[tid], red, tid);
    offv[b * 256 + tid] = SCALEV * (vg + uu * dkq + cv * (dwq + 4096.0f * dkq));
}

// ---- fused F->T per (b, 64-col slice): F = G_b Z -> LDS; T = Wv' F + epilogue ----
__global__ __launch_bounds__(256, 2) void gemm_FT(const ushort* __restrict__ Gbf,
                                                  const ushort* __restrict__ ZT,
                                                  const ushort* __restrict__ Wvb,
                                                  ushort* __restrict__ Tbf,
                                                  const float* __restrict__ u,
                                                  const float* __restrict__ cvec,
                                                  const float* __restrict__ r_,
                                                  const float* __restrict__ hb) {
    __shared__ __align__(16) ushort zt[64 * 256];
    const int blk = blockIdx.x, tid = threadIdx.x;
    const int b = blk >> 2, j0 = (blk & 3) * 64;
    const int wave = tid >> 6, lane = tid & 63;
    const int m = lane & 15, qq = lane >> 4;
    const int q8 = qq * 8;
    f32x4 acc[4][4];

    // step 1: F[row, j0+col] = sum_k G_b[row,k] * Z[k, j0+col]  (Z^T from global)
    #pragma unroll
    for (int a = 0; a < 4; ++a)
        #pragma unroll
        for (int q = 0; q < 4; ++q) acc[a][q] = (f32x4){0.f, 0.f, 0.f, 0.f};
    const ushort* Gb = Gbf + (long)b * 65536;
    const ushort* Zs = ZT + (long)j0 * 256;
    #pragma unroll
    for (int kk = 0; kk < 8; ++kk) {
        short8 af[4], bv[4];
        #pragma unroll
        for (int a = 0; a < 4; ++a)
            af[a] = *(const short8*)&Gb[(long)(wave * 64 + a * 16 + m) * 256 + kk * 32 + q8];
        #pragma unroll
        for (int q = 0; q < 4; ++q)
            bv[q] = *(const short8*)&Zs[(long)(q * 16 + m) * 256 + kk * 32 + q8];
        #pragma unroll
        for (int a = 0; a < 4; ++a)
            #pragma unroll
            for (int q = 0; q < 4; ++q)
                acc[a][q] = MFMA16(af[a], bv[q], acc[a][q]);
    }
    // store F -> LDS as zt[col][row] bf16, XOR-swizzled on row
    #pragma unroll
    for (int a = 0; a < 4; ++a)
        #pragma unroll
        for (int q = 0; q < 4; ++q) {
            const int col = q * 16 + m;
            const int rowb = wave * 64 + a * 16 + qq * 4;
            const ushort2 p01 = f2bf2(acc[a][q][0], acc[a][q][1]);
            const ushort2 p23 = f2bf2(acc[a][q][2], acc[a][q][3]);
            ushort4 w4; w4.x = p01.x; w4.y = p01.y; w4.z = p23.x; w4.w = p23.y;
            *(ushort4*)&zt[col * 256 + (rowb ^ ((col & 7) << 3))] = w4;
        }
    __syncthreads();

    // step 2: T[row, j0+col] = sum_i Wv'[row,i] * F[i, j0+col]  + epilogue
    #pragma unroll
    for (int a = 0; a < 4; ++a)
        #pragma unroll
        for (int q = 0; q < 4; ++q) acc[a][q] = (f32x4){0.f, 0.f, 0.f, 0.f};
    #pragma unroll
    for (int kk = 0; kk < 8; ++kk) {
        short8 af[4], bv[4];
        #pragma unroll
        for (int a = 0; a < 4; ++a)
            af[a] = *(const short8*)&Wvb[(long)(wave * 64 + a * 16 + m) * 256 + kk * 32 + q8];
        #pragma unroll
        for (int q = 0; q < 4; ++q) {
            const int col = q * 16 + m;
            bv[q] = *(const short8*)&zt[col * 256 + ((kk * 32 + q8) ^ ((col & 7) << 3))];
        }
        #pragma unroll
        for (int a = 0; a < 4; ++a)
            #pragma unroll
            for (int q = 0; q < 4; ++q)
                acc[a][q] = MFMA16(af[a], bv[q], acc[a][q]);
    }
    const int rq4 = qq * 4;
    #pragma unroll
    for (int a = 0; a < 4; ++a) {
        #pragma unroll
        for (int q = 0; q < 4; ++q) {
            const int cg = j0 + q * 16 + m;
            const float rv = r_[cg];
            const float t2 = hb[b * 256 + cg] + 4096.0f * rv;
            #pragma unroll
            for (int reg = 0; reg < 4; ++reg) {
                const int row = wave * 64 + a * 16 + rq4 + reg;
                const float val = SCALEV * (acc[a][q][reg] + u[b * 256 + row] * rv
                                            + cvec[512 + row] * t2);
                Tbf[(long)b * 65536 + (long)row * 256 + cg] = f2bf(val);
            }
        }
    }
}

// ---- out_b = T_b x_b + off_b via MFMA; 64-pixel tiles; grid (64, 8) ----
__global__ __launch_bounds__(256) void out_mfma(const ushort* __restrict__ Tbf,
                                                const float* __restrict__ x,
                                                const float* __restrict__ offv,
                                                float* __restrict__ out) {
    __shared__ __align__(16) ushort Bs[64 * 264];
    const int tid = threadIdx.x;
    const int p0 = blockIdx.x * 64;
    const int b = blockIdx.y;
    const float* xb = x + (long)b * CC * NPIX;
    const ushort* Tb = Tbf + (long)b * 65536;

    const int c = tid & 15, kq = tid >> 4;
    #pragma unroll
    for (int kt = 0; kt < 4; ++kt) {
        const int k4 = kt * 64 + kq * 4;
        const int p = c * 4;
        const float4 v0 = *(const float4*)&xb[(long)(k4 + 0) * NPIX + p0 + p];
        const float4 v1 = *(const float4*)&xb[(long)(k4 + 1) * NPIX + p0 + p];
        const float4 v2 = *(const float4*)&xb[(long)(k4 + 2) * NPIX + p0 + p];
        const float4 v3 = *(const float4*)&xb[(long)(k4 + 3) * NPIX + p0 + p];
        ushort2 a01, a23;
        ushort4 w;
        a01 = f2bf2(v0.x, v1.x); a23 = f2bf2(v2.x, v3.x);
        w.x = a01.x; w.y = a01.y; w.z = a23.x; w.w = a23.y;
        *(ushort4*)&Bs[(p + 0) * 264 + k4] = w;
        a01 = f2bf2(v0.y, v1.y); a23 = f2bf2(v2.y, v3.y);
        w.x = a01.x; w.y = a01.y; w.z = a23.x; w.w = a23.y;
        *(ushort4*)&Bs[(p + 1) * 264 + k4] = w;
        a01 = f2bf2(v0.z, v1.z); a23 = f2bf2(v2.z, v3.z);
        w.x = a01.x; w.y = a01.y; w.z = a23.x; w.w = a23.y;
        *(ushort4*)&Bs[(p + 2) * 264 + k4] = w;
        a01 = f2bf2(v0.w, v1.w); a23 = f2bf2(v2.w, v3.w);
        w.x = a01.x; w.y = a01.y; w.z = a23.x; w.w = a23.y;
        *(ushort4*)&Bs[(p + 3) * 264 + k4] = w;
    }
    __syncthreads();

    const int wave = tid >> 6, lane = tid & 63;
    const int wr = wave * 64;
    const int m = lane & 15, q8 = (lane >> 4) * 8;
    f32x4 acc[4][4];
    #pragma unroll
    for (int a = 0; a < 4; ++a)
        #pragma unroll
        for (int q = 0; q < 4; ++q) acc[a][q] = (f32x4){0.f, 0.f, 0.f, 0.f};

    #pragma unroll
    for (int kk = 0; kk < 8; ++kk) {
        short8 af[4], bfv[4];
        #pragma unroll
        for (int a = 0; a < 4; ++a)
            af[a] = *(const short8*)&Tb[(long)(wr + a * 16 + m) * 256 + kk * 32 + q8];
        #pragma unroll
        for (int q = 0; q < 4; ++q)
            bfv[q] = *(const short8*)&Bs[(q * 16 + m) * 264 + kk * 32 + q8];
        #pragma unroll
        for (int a = 0; a < 4; ++a)
            #pragma unroll
            for (int q = 0; q < 4; ++q)
                acc[a][q] = MFMA16(af[a], bfv[q], acc[a][q]);
    }

    const int rq = (lane >> 4) * 4;
    #pragma unroll
    for (int a = 0; a < 4; ++a) {
        #pragma unroll
        for (int reg = 0; reg < 4; ++reg) {
            const int row = wr + a * 16 + rq + reg;
            const float off_ = offv[b * CC + row];
            float* orow = &out[((long)b * CC + row) * NPIX + p0];
            #pragma unroll
            for (int q = 0; q < 4; ++q)
                orow[q * 16 + m] = acc[a][q][reg] + off_;
        }
    }
}

extern "C" void kernel_launch(void* const* d_in, const int* in_sizes, int n_in,
                              void* d_out, int out_size, void* d_ws, size_t ws_size,
                              hipStream_t stream) {
    const float* x     = (const float*)d_in[0];
    const float* Wq    = (const float*)d_in[1];
    const float* bq    = (const float*)d_in[2];
    const float* gq    = (const float*)d_in[3];
    const float* betaq = (const float*)d_in[4];
    const float* Wk    = (const float*)d_in[5];
    const float* bk    = (const float*)d_in[6];
    const float* gk    = (const float*)d_in[7];
    const float* betak = (const float*)d_in[8];
    const float* Wv    = (const float*)d_in[9];
    const float* bv    = (const float*)d_in[10];
    const float* gv    = (const float*)d_in[11];
    const float* betav = (const float*)d_in[12];
    float* ws = (float*)d_ws;

    float*  Pg   = ws + OFF_PG;
    float*  Sp   = ws + OFF_SP;
    float*  S    = ws + OFF_S;
    float*  Ghat = ws + OFF_GHAT;
    float*  Xbar = ws + OFF_XBAR;
    float*  Wp   = ws + OFF_WP;
    float*  WkTf = ws + OFF_WKTF;
    float*  WvTf = ws + OFF_WVTF;
    float*  cvec = ws + OFF_CVEC;
    float*  U    = ws + OFF_U;
    float*  Hb   = ws + OFF_HB;
    float*  R    = ws + OFF_R;
    float*  OffV = ws + OFF_OFFV;
    ushort* Gbf  = (ushort*)(ws + OFF_GBF);
    ushort* WqT  = (ushort*)(ws + OFF_WQT);
    ushort* WkT  = (ushort*)(ws + OFF_WKT);
    ushort* Wvb  = (ushort*)(ws + OFF_WVB);
    ushort* ZT   = (ushort*)(ws + OFF_ZT);
    ushort* Tbf  = (ushort*)(ws + OFF_TBF);

    gram_mfma<<<dim3(16, 8, 3), 256, 0, stream>>>(x, Pg, Sp, Ghat);
    reduce_mirror<<<385, 256, 0, stream>>>(Pg, Sp, Gbf, Ghat, S, Xbar);
    stats_quad<<<dim3(64, 3), 256, 0, stream>>>(Wq, Wk, Wv, Ghat, Xbar,
                                                bq, gq, betaq, bk, gk, betak,
                                                bv, gv, betav, Wp, cvec,
                                                WqT, WkT, Wvb, WkTf, WvTf);
    zmidabc<<<12, 256, 0, stream>>>(WkT, WqT, ZT, Wp, WkTf, WvTf, S, cvec, Gbf,
                                    U, Hb, R, OffV);
    gemm_FT<<<32, 256, 0, stream>>>(Gbf, ZT, Wvb, Tbf, U, cvec, R, Hb);
    out_mfma<<<dim3(64, 8), 256, 0, stream>>>(Tbf, x, OffV, (float*)d_out);
}

// Round 8
// 190.209 us; speedup vs baseline: 2.4932x; 1.1431x over previous
//
#include <hip/hip_runtime.h>
#include <hip/hip_bf16.h>

// PatchAttentionLayer R14: 7 dispatches; matvec chain 4-way split + GEMM-overlapped.
//   gram: ks=16 (384 blocks) -> Pg partials; zeroes Ghat + Acc; rowsums.
//   reduce_mirror: 385 blocks -> Gbf (mirrored), Ghat(atomic), S, xbar.
//   stats_quad: grid (64,3) -> Wp, transposes, cvec.
//   zmida: {Z GEMM (4) | u,w 4-way (32, atomic) | y,r 4-way (4, atomic)}.
//   bcF2:  {F = G_b Z GEMM -> FT (32) | h 4-way (32) | g 4-way (32) | scalars (1)}.
//   tvg:   {T = Wv' F + rank-1 epilogue -> Tbf (32) | vg 4-way (32, atomic)}.
//   out_mfma: out = T x + off; off computed inline from VGacc/Uacc/scalars.
// Every chain stage ( <=64-deep ) runs alongside >=32 GEMM blocks -> latency hidden.

#define BB 8
#define CC 256
#define NPIX 4096
#define PTOT 32768
#define EPSV 1e-5f
#define SCALEV 0.125f

// ---- workspace layout (float offsets) ----
#define OFF_PG    0L          // 384*16384 = 6291456
#define OFF_SP    6291456L    // 32768
#define OFF_S     6324224L    // 2048
#define OFF_GHAT  6326272L    // 65536
#define OFF_XBAR  6391808L    // 256
#define OFF_WP    6392064L    // 196608
#define OFF_WKTF  6588672L    // 65536
#define OFF_WVTF  6654208L    // 65536
#define OFF_CVEC  6719744L    // 768
#define OFF_ACC   6720512L    // 12288
#define OFF_GBF   6732800L    // 262144 (8*65536 ushort)
#define OFF_WQT   6994944L    // 32768
#define OFF_WKT   7027712L    // 32768
#define OFF_WVB   7060480L    // 32768
#define OFF_ZT    7093248L    // 32768
#define OFF_FT    7126016L    // 262144 (ushort)
#define OFF_TBF   7388160L    // 262144 (ushort)
// total 7650304 floats = 30.6 MB

// accumulator offsets inside OFF_ACC (floats); zeroed by gram spare blocks
#define ACC_U    0      // 8*256
#define ACC_W    2048   // 8*256
#define ACC_Y    4096   // 256
#define ACC_R    4352   // 256
#define ACC_H    4608   // 8*256
#define ACC_G    6656   // 8*256
#define ACC_VG   8704   // 8*256
#define ACC_SCAL 10752  // [0]=dkq, [1+b]=dwq[b]
#define ACC_TOT  12288  // zeroed region (12 blocks x 1024)

typedef __attribute__((ext_vector_type(8))) short short8;
typedef __attribute__((ext_vector_type(4))) float f32x4;

#define MFMA16(a, b, c) __builtin_amdgcn_mfma_f32_16x16x32_bf16((a), (b), (c), 0, 0, 0)

__device__ __forceinline__ ushort f2bf(float f) {
    union { float f; unsigned u; } v; v.f = f;
    const unsigned r = (v.u + 0x7FFFu + ((v.u >> 16) & 1u)) >> 16;
    return (ushort)r;
}

__device__ __forceinline__ float bf2f(ushort u) {
    union { unsigned u; float f; } v; v.u = ((unsigned)u) << 16;
    return v.f;
}

__device__ __forceinline__ ushort2 f2bf2(float a, float b) {
    __hip_bfloat162 h = __float22bfloat162_rn(float2{a, b});
    union { __hip_bfloat162 h; ushort2 u; } v; v.h = h;
    return v.u;
}

__device__ __forceinline__ float block_reduce(float v, float* red, int tid) {
    red[tid] = v; __syncthreads();
    for (int st = 128; st > 0; st >>= 1) {
        if (tid < st) red[tid] += red[tid + st];
        __syncthreads();
    }
    float r = red[0]; __syncthreads();
    return r;
}

__device__ __forceinline__ float2 wred2(float a, float b, float* red8, int tid) {
    #pragma unroll
    for (int s = 32; s > 0; s >>= 1) {
        a += __shfl_xor(a, s);
        b += __shfl_xor(b, s);
    }
    if ((tid & 63) == 0) { red8[(tid >> 6) * 2] = a; red8[(tid >> 6) * 2 + 1] = b; }
    __syncthreads();
    const float ra = red8[0] + red8[2] + red8[4] + red8[6];
    const float rb = red8[1] + red8[3] + red8[5] + red8[7];
    __syncthreads();
    return float2{ra, rb};
}

// ---- Gram via MFMA: 128x128 upper tiles, ks=16; zeroes Ghat + Acc ----
__global__ __launch_bounds__(256, 2) void gram_mfma(const float* __restrict__ x,
                                                    float* __restrict__ Pg,
                                                    float* __restrict__ Sp,
                                                    float* __restrict__ Ghat,
                                                    float* __restrict__ Acc) {
    __shared__ __align__(16) ushort Ab[128 * 72];
    __shared__ __align__(16) ushort Bb[128 * 72];
    __shared__ float rs[128];
    const int tid = threadIdx.x;
    const int ks = blockIdx.x, b = blockIdx.y, tt = blockIdx.z;
    const int lb = (tt * 8 + b) * 16 + ks;
    if (lb < 64) {
        #pragma unroll
        for (int i = 0; i < 4; ++i) Ghat[lb * 1024 + i * 256 + tid] = 0.f;
    } else if (lb < 76) {
        const int base = (lb - 64) * 1024;
        #pragma unroll
        for (int i = 0; i < 4; ++i) Acc[base + i * 256 + tid] = 0.f;
    }
    const int it = (tt == 1) ? 1 : 0;
    const int jt = (tt == 0) ? 0 : 1;
    const bool diag = (tt < 2);
    const int i0 = it * 128, j0 = jt * 128, k0 = ks * 256;
    const float* xb = x + (long)b * CC * NPIX;
    const int c = tid & 15, rp = tid >> 4;
    const int wave = tid >> 6, lane = tid & 63;
    const int wr = (wave >> 1) * 64, wc = (wave & 1) * 64;
    const int m = lane & 15, q8 = (lane >> 4) * 8;

    if (tid < 128) rs[tid] = 0.f;
    float rloc[8] = {};
    f32x4 acc[4][4];
    #pragma unroll
    for (int a = 0; a < 4; ++a)
        #pragma unroll
        for (int q = 0; q < 4; ++q) acc[a][q] = (f32x4){0.f, 0.f, 0.f, 0.f};

    const float* Abase = xb + (long)i0 * NPIX + k0 + c * 4;
    const float* Bbase = xb + (long)j0 * NPIX + k0 + c * 4;

    float4 va[8], vb[8];
    #pragma unroll
    for (int pp = 0; pp < 8; ++pp)
        va[pp] = *(const float4*)&Abase[(long)(pp * 16 + rp) * NPIX];
    if (!diag) {
        #pragma unroll
        for (int pp = 0; pp < 8; ++pp)
            vb[pp] = *(const float4*)&Bbase[(long)(pp * 16 + rp) * NPIX];
    }

    for (int kc = 0; kc < 256; kc += 64) {
        __syncthreads();
        #pragma unroll
        for (int pp = 0; pp < 8; ++pp) {
            const int row = pp * 16 + rp;
            const float4 v = va[pp];
            rloc[pp] += v.x + v.y + v.z + v.w;
            const ushort2 w01 = f2bf2(v.x, v.y);
            const ushort2 w23 = f2bf2(v.z, v.w);
            ushort4 w; w.x = w01.x; w.y = w01.y; w.z = w23.x; w.w = w23.y;
            *(ushort4*)&Ab[row * 72 + c * 4] = w;
        }
        if (!diag) {
            #pragma unroll
            for (int pp = 0; pp < 8; ++pp) {
                const int row = pp * 16 + rp;
                const float4 v = vb[pp];
                const ushort2 w01 = f2bf2(v.x, v.y);
                const ushort2 w23 = f2bf2(v.z, v.w);
                ushort4 w; w.x = w01.x; w.y = w01.y; w.z = w23.x; w.w = w23.y;
                *(ushort4*)&Bb[row * 72 + c * 4] = w;
            }
        }
        const int kn = kc + 64;
        if (kn < 256) {
            #pragma unroll
            for (int pp = 0; pp < 8; ++pp)
                va[pp] = *(const float4*)&Abase[(long)(pp * 16 + rp) * NPIX + kn];
            if (!diag) {
                #pragma unroll
                for (int pp = 0; pp < 8; ++pp)
                    vb[pp] = *(const float4*)&Bbase[(long)(pp * 16 + rp) * NPIX + kn];
            }
        }
        __syncthreads();
        const ushort* Bsrc = diag ? Ab : Bb;
        #pragma unroll
        for (int kk = 0; kk < 2; ++kk) {
            short8 af[4], bfv[4];
            #pragma unroll
            for (int a = 0; a < 4; ++a)
                af[a] = *(const short8*)&Ab[(wr + a * 16 + m) * 72 + kk * 32 + q8];
            #pragma unroll
            for (int q = 0; q < 4; ++q)
                bfv[q] = *(const short8*)&Bsrc[(wc + q * 16 + m) * 72 + kk * 32 + q8];
            #pragma unroll
            for (int a = 0; a < 4; ++a)
                #pragma unroll
                for (int q = 0; q < 4; ++q)
                    acc[a][q] = MFMA16(af[a], bfv[q], acc[a][q]);
        }
    }
    if (diag) {
        #pragma unroll
        for (int pp = 0; pp < 8; ++pp) atomicAdd(&rs[pp * 16 + rp], rloc[pp]);
        __syncthreads();
        if (tid < 128) Sp[(((long)ks * 8 + b) * 2 + it) * 128 + tid] = rs[tid];
    }
    float* Pt = Pg + (((long)ks * 8 + b) * 3 + tt) * 16384;
    const int rq = (lane >> 4) * 4;
    #pragma unroll
    for (int a = 0; a < 4; ++a) {
        #pragma unroll
        for (int q = 0; q < 4; ++q) {
            const int col = wc + q * 16 + m;
            #pragma unroll
            for (int reg = 0; reg < 4; ++reg)
                Pt[(long)(wr + a * 16 + rq + reg) * 128 + col] = acc[a][q][reg];
        }
    }
}

// ---- reduce partials -> Gbf (mirrored), Ghat (atomic); S; xbar. grid 385 ----
__global__ __launch_bounds__(256) void reduce_mirror(const float* __restrict__ Pg,
                                                     const float* __restrict__ Sp,
                                                     ushort* __restrict__ Gbf,
                                                     float* __restrict__ Ghat,
                                                     float* __restrict__ S,
                                                     float* __restrict__ xbar) {
    const int blk = blockIdx.x, tid = threadIdx.x;
    if (blk == 384) {
        const int it2 = tid >> 7, rr = tid & 127;
        float xacc = 0.f;
        for (int b = 0; b < BB; ++b) {
            float acc = 0.f;
            #pragma unroll
            for (int ks = 0; ks < 16; ++ks)
                acc += Sp[(((long)ks * 8 + b) * 2 + it2) * 128 + rr];
            S[b * 256 + tid] = acc;
            xacc += acc;
        }
        xbar[tid] = xacc * (1.0f / PTOT);
        return;
    }
    __shared__ float tile[32][33];
    const int tt = blk >> 7;
    const int sub = (blk >> 3) & 15;
    const int b = blk & 7;
    const int sr = (sub >> 2) * 32, sc = (sub & 3) * 32;
    const int it = (tt == 1) ? 1 : 0;
    const int jt = (tt == 0) ? 0 : 1;
    const bool offd = (tt == 2);
    const int gi0 = it * 128 + sr, gj0 = jt * 128 + sc;
    const int r = tid >> 3, c4 = (tid & 7) * 4;
    const float inv = 1.0f / PTOT;

    float s0 = 0.f, s1 = 0.f, s2 = 0.f, s3 = 0.f;
    #pragma unroll
    for (int ks = 0; ks < 16; ++ks) {
        const float4 v = *(const float4*)&Pg[(((long)ks * 8 + b) * 3 + tt) * 16384
                                             + (long)(sr + r) * 128 + sc + c4];
        s0 += v.x; s1 += v.y; s2 += v.z; s3 += v.w;
    }
    ushort4 w;
    w.x = f2bf(s0); w.y = f2bf(s1); w.z = f2bf(s2); w.w = f2bf(s3);
    *(ushort4*)&Gbf[(long)b * 65536 + (long)(gi0 + r) * 256 + gj0 + c4] = w;
    float* gd = &Ghat[(long)(gi0 + r) * 256 + gj0 + c4];
    atomicAdd(gd + 0, s0 * inv);
    atomicAdd(gd + 1, s1 * inv);
    atomicAdd(gd + 2, s2 * inv);
    atomicAdd(gd + 3, s3 * inv);
    if (offd) {
        tile[r][c4 + 0] = s0; tile[r][c4 + 1] = s1;
        tile[r][c4 + 2] = s2; tile[r][c4 + 3] = s3;
        __syncthreads();
        const float t0 = tile[c4 + 0][r], t1 = tile[c4 + 1][r];
        const float t2 = tile[c4 + 2][r], t3 = tile[c4 + 3][r];
        ushort4 tw;
        tw.x = f2bf(t0); tw.y = f2bf(t1); tw.z = f2bf(t2); tw.w = f2bf(t3);
        *(ushort4*)&Gbf[(long)b * 65536 + (long)(gj0 + r) * 256 + gi0 + c4] = tw;
        float* gm = &Ghat[(long)(gj0 + r) * 256 + gi0 + c4];
        atomicAdd(gm + 0, t0 * inv);
        atomicAdd(gm + 1, t1 * inv);
        atomicAdd(gm + 2, t2 * inv);
        atomicAdd(gm + 3, t3 * inv);
    }
}

// ---- BN stats; 4 output channels per block, grid (64,3) ----
__global__ __launch_bounds__(256) void stats_quad(const float* __restrict__ Wq, const float* __restrict__ Wk,
                           const float* __restrict__ Wv, const float* __restrict__ Ghat,
                           const float* __restrict__ xbar,
                           const float* bq, const float* gq, const float* betaq,
                           const float* bk, const float* gk, const float* betak,
                           const float* bv, const float* gv, const float* betav,
                           float* __restrict__ Wp, float* __restrict__ cvec,
                           ushort* __restrict__ WqT, ushort* __restrict__ WkT,
                           ushort* __restrict__ Wvb, float* __restrict__ WkTf,
                           float* __restrict__ WvTf) {
    const int og = blockIdx.x, t = blockIdx.y, tid = threadIdx.x;
    const int o0 = og * 4;
    const float* Wt  = t == 0 ? Wq : (t == 1 ? Wk : Wv);
    const float* bt  = t == 0 ? bq : (t == 1 ? bk : bv);
    const float* gt  = t == 0 ? gq : (t == 1 ? gk : gv);
    const float* bet = t == 0 ? betaq : (t == 1 ? betak : betav);
    __shared__ float wrows[4][256];
    __shared__ float red8[8];
    #pragma unroll
    for (int i = 0; i < 4; ++i) wrows[i][tid] = Wt[(o0 + i) * 256 + tid];
    const float xb = xbar[tid];
    __syncthreads();
    const float* grow = Ghat + (long)tid * 256;
    float tj[4] = {0.f, 0.f, 0.f, 0.f};
    #pragma unroll 8
    for (int k = 0; k < 256; k += 4) {
        const float4 g = *(const float4*)&grow[k];
        #pragma unroll
        for (int i = 0; i < 4; ++i)
            tj[i] += g.x * wrows[i][k]     + g.y * wrows[i][k + 1]
                   + g.z * wrows[i][k + 2] + g.w * wrows[i][k + 3];
    }
    #pragma unroll
    for (int i = 0; i < 4; ++i) {
        const int o = o0 + i;
        const float wv = wrows[i][tid];
        const float2 qw = wred2(wv * tj[i], wv * xb, red8, tid);
        const float bo = bt[o];
        const float mu = qw.y + bo;
        const float var = qw.x + 2.f * bo * mu - bo * bo - mu * mu;
        const float a = gt[o] * rsqrtf(var + EPSV);
        const float wpv = a * wv;
        Wp[(long)t * 65536 + o * 256 + tid] = wpv;
        const ushort wb = f2bf(wpv);
        if (t == 0) {
            WqT[(long)tid * 256 + o] = wb;
        } else if (t == 1) {
            WkT[(long)tid * 256 + o] = wb;
            WkTf[(long)tid * 256 + o] = wpv;
        } else {
            Wvb[(long)o * 256 + tid] = wb;
            WvTf[(long)tid * 256 + o] = wpv;
        }
        if (tid == 0) cvec[t * 256 + o] = a * (bo - mu) + bet[o];
    }
}

// ---- 128x128 MFMA tile, K=256, fragments direct from L2; D[col][row] bf16 ----
__device__ __forceinline__ void gemm_tile0(const ushort* __restrict__ Ab,
                                           const ushort* __restrict__ Bb,
                                           ushort* __restrict__ Db,
                                           int m0, int n0, int tid) {
    const int wave = tid >> 6, lane = tid & 63;
    const int wr = (wave >> 1) * 64, wc = (wave & 1) * 64;
    const int m = lane & 15, q8 = (lane >> 4) * 8;
    f32x4 acc[4][4];
    #pragma unroll
    for (int a = 0; a < 4; ++a)
        #pragma unroll
        for (int q = 0; q < 4; ++q) acc[a][q] = (f32x4){0.f, 0.f, 0.f, 0.f};
    #pragma unroll
    for (int kk = 0; kk < 8; ++kk) {
        short8 af[4], bfv[4];
        #pragma unroll
        for (int a = 0; a < 4; ++a)
            af[a] = *(const short8*)&Ab[(long)(m0 + wr + a * 16 + m) * 256 + kk * 32 + q8];
        #pragma unroll
        for (int q = 0; q < 4; ++q)
            bfv[q] = *(const short8*)&Bb[(long)(n0 + wc + q * 16 + m) * 256 + kk * 32 + q8];
        #pragma unroll
        for (int a = 0; a < 4; ++a)
            #pragma unroll
            for (int q = 0; q < 4; ++q)
                acc[a][q] = MFMA16(af[a], bfv[q], acc[a][q]);
    }
    const int rq = (lane >> 4) * 4;
    #pragma unroll
    for (int a = 0; a < 4; ++a) {
        #pragma unroll
        for (int q = 0; q < 4; ++q) {
            const int col = n0 + wc + q * 16 + m;
            #pragma unroll
            for (int reg = 0; reg < 4; ++reg)
                Db[(long)col * 256 + (m0 + wr + a * 16 + rq + reg)] = f2bf(acc[a][q][reg]);
        }
    }
}

// ---- zmida: {Z GEMM (0-3) | u,w 4-way (4-35) | y,r 4-way (36-39)} ----
__global__ __launch_bounds__(256) void zmida(const ushort* __restrict__ WkT,
                                             const ushort* __restrict__ WqT,
                                             ushort* __restrict__ ZT,
                                             const float* __restrict__ Wp,
                                             const float* __restrict__ WkTf,
                                             const float* __restrict__ WvTf,
                                             const float* __restrict__ S,
                                             const float* __restrict__ cvec,
                                             float* __restrict__ Acc) {
    const int blk = blockIdx.x, tid = threadIdx.x;
    __shared__ float sa[64], sb[64];
    if (blk < 4) {
        gemm_tile0(WkT, WqT, ZT, (blk >> 1) * 128, (blk & 1) * 128, tid);
        return;
    }
    if (blk < 36) {
        const int b = (blk - 4) >> 2, j0 = ((blk - 4) & 3) * 64;
        if (tid < 64) sa[tid] = S[b * 256 + j0 + tid];
        __syncthreads();
        float uu = 0.f, ww = 0.f;
        #pragma unroll 8
        for (int i = 0; i < 64; ++i) {
            const float sv = sa[i];
            uu += WvTf[(long)(j0 + i) * 256 + tid] * sv;
            ww += WkTf[(long)(j0 + i) * 256 + tid] * sv;
        }
        atomicAdd(&Acc[ACC_U + b * 256 + tid], uu);
        atomicAdd(&Acc[ACC_W + b * 256 + tid], ww);
    } else {
        const int o0 = (blk - 36) * 64;
        if (tid < 64) { sa[tid] = cvec[o0 + tid]; sb[tid] = cvec[256 + o0 + tid]; }
        __syncthreads();
        float yy = 0.f, rr = 0.f;
        #pragma unroll 8
        for (int i = 0; i < 64; ++i) {
            yy += Wp[65536L + (long)(o0 + i) * 256 + tid] * sa[i];
            rr += Wp[(long)(o0 + i) * 256 + tid] * sb[i];
        }
        atomicAdd(&Acc[ACC_Y + tid], yy);
        atomicAdd(&Acc[ACC_R + tid], rr);
    }
}

// ---- bcF2: {F GEMM (0-31) | h 4-way (32-63) | g 4-way (64-95) | scalars (96)} ----
__global__ __launch_bounds__(256) void bcF2(const ushort* __restrict__ Gbf,
                                            const ushort* __restrict__ ZT,
                                            ushort* __restrict__ FT,
                                            const float* __restrict__ Wp,
                                            const float* __restrict__ cvec,
                                            float* __restrict__ Acc) {
    const int blk = blockIdx.x, tid = threadIdx.x;
    __shared__ float sa[64];
    __shared__ float red[256];
    if (blk < 32) {
        const int bz = blk >> 2, t = blk & 3;
        gemm_tile0(Gbf + (long)bz * 65536, ZT, FT + (long)bz * 65536,
                   (t >> 1) * 128, (t & 1) * 128, tid);
        return;
    }
    if (blk < 64) {
        const int b = (blk - 32) >> 2, o0 = ((blk - 32) & 3) * 64;
        if (tid < 64) sa[tid] = Acc[ACC_W + b * 256 + o0 + tid];
        __syncthreads();
        float hh = 0.f;
        #pragma unroll 8
        for (int i = 0; i < 64; ++i)
            hh += Wp[(long)(o0 + i) * 256 + tid] * sa[i];
        atomicAdd(&Acc[ACC_H + b * 256 + tid], hh);
    } else if (blk < 96) {
        const int b = (blk - 64) >> 2, o0 = ((blk - 64) & 3) * 64;
        if (tid < 64) sa[tid] = Acc[ACC_Y + o0 + tid];
        __syncthreads();
        float gg = 0.f;
        #pragma unroll 8
        for (int i = 0; i < 64; ++i)
            gg += bf2f(Gbf[(long)b * 65536 + (long)(o0 + i) * 256 + tid]) * sa[i];
        atomicAdd(&Acc[ACC_G + b * 256 + tid], gg);
    } else {
        const float cq = cvec[tid], ck = cvec[256 + tid];
        const float dkq = block_reduce(cq * ck, red, tid);
        if (tid == 0) Acc[ACC_SCAL] = dkq;
        for (int b = 0; b < BB; ++b) {
            const float dwq = block_reduce(Acc[ACC_W + b * 256 + tid] * cq, red, tid);
            if (tid == 0) Acc[ACC_SCAL + 1 + b] = dwq;
        }
    }
}

// ---- tvg: {T GEMM + epilogue (0-31) | vg 4-way (32-63)} ----
__global__ __launch_bounds__(256) void tvg(const ushort* __restrict__ Wvb,
                                           const ushort* __restrict__ FT,
                                           ushort* __restrict__ Tbf,
                                           const float* __restrict__ WvTf,
                                           const float* __restrict__ cvec,
                                           float* __restrict__ Acc) {
    const int blk = blockIdx.x, tid = threadIdx.x;
    __shared__ float sa[64];
    if (blk < 32) {
        const int bz = blk >> 2, t = blk & 3;
        const int m0 = (t >> 1) * 128, n0 = (t & 1) * 128;
        const ushort* Fb = FT + (long)bz * 65536;
        const int wave = tid >> 6, lane = tid & 63;
        const int wr = (wave >> 1) * 64, wc = (wave & 1) * 64;
        const int m = lane & 15, q8 = (lane >> 4) * 8;
        f32x4 acc[4][4];
        #pragma unroll
        for (int a = 0; a < 4; ++a)
            #pragma unroll
            for (int q = 0; q < 4; ++q) acc[a][q] = (f32x4){0.f, 0.f, 0.f, 0.f};
        #pragma unroll
        for (int kk = 0; kk < 8; ++kk) {
            short8 af[4], bfv[4];
            #pragma unroll
            for (int a = 0; a < 4; ++a)
                af[a] = *(const short8*)&Wvb[(long)(m0 + wr + a * 16 + m) * 256 + kk * 32 + q8];
            #pragma unroll
            for (int q = 0; q < 4; ++q)
                bfv[q] = *(const short8*)&Fb[(long)(n0 + wc + q * 16 + m) * 256 + kk * 32 + q8];
            #pragma unroll
            for (int a = 0; a < 4; ++a)
                #pragma unroll
                for (int q = 0; q < 4; ++q)
                    acc[a][q] = MFMA16(af[a], bfv[q], acc[a][q]);
        }
        const int rq = (lane >> 4) * 4;
        #pragma unroll
        for (int a = 0; a < 4; ++a) {
            #pragma unroll
            for (int q = 0; q < 4; ++q) {
                const int col = n0 + wc + q * 16 + m;
                const float rv = Acc[ACC_R + col];
                const float t2 = Acc[ACC_H + bz * 256 + col] + 4096.0f * rv;
                #pragma unroll
                for (int reg = 0; reg < 4; ++reg) {
                    const int row = m0 + wr + a * 16 + rq + reg;
                    const float val = SCALEV * (acc[a][q][reg]
                                                + Acc[ACC_U + bz * 256 + row] * rv
                                                + cvec[512 + row] * t2);
                    Tbf[(long)bz * 65536 + (long)row * 256 + col] = f2bf(val);
                }
            }
        }
    } else {
        const int b = (blk - 32) >> 2, j0 = ((blk - 32) & 3) * 64;
        if (tid < 64) sa[tid] = Acc[ACC_G + b * 256 + j0 + tid];
        __syncthreads();
        float vg = 0.f;
        #pragma unroll 8
        for (int i = 0; i < 64; ++i)
            vg += WvTf[(long)(j0 + i) * 256 + tid] * sa[i];
        atomicAdd(&Acc[ACC_VG + b * 256 + tid], vg);
    }
}

// ---- out = T x + off (off computed inline); grid (64, 8) ----
__global__ __launch_bounds__(256) void out_mfma(const ushort* __restrict__ Tbf,
                                                const float* __restrict__ x,
                                                const float* __restrict__ Acc,
                                                const float* __restrict__ cvec,
                                                float* __restrict__ out) {
    __shared__ __align__(16) ushort Bs[64 * 264];
    const int tid = threadIdx.x;
    const int p0 = blockIdx.x * 64;
    const int b = blockIdx.y;
    const float* xb = x + (long)b * CC * NPIX;
    const ushort* Tb = Tbf + (long)b * 65536;
    const float dkq = Acc[ACC_SCAL];
    const float dwqb = Acc[ACC_SCAL + 1 + b];

    const int c = tid & 15, kq = tid >> 4;
    #pragma unroll
    for (int kt = 0; kt < 4; ++kt) {
        const int k4 = kt * 64 + kq * 4;
        const int p = c * 4;
        const float4 v0 = *(const float4*)&xb[(long)(k4 + 0) * NPIX + p0 + p];
        const float4 v1 = *(const float4*)&xb[(long)(k4 + 1) * NPIX + p0 + p];
        const float4 v2 = *(const float4*)&xb[(long)(k4 + 2) * NPIX + p0 + p];
        const float4 v3 = *(const float4*)&xb[(long)(k4 + 3) * NPIX + p0 + p];
        ushort2 a01, a23;
        ushort4 w;
        a01 = f2bf2(v0.x, v1.x); a23 = f2bf2(v2.x, v3.x);
        w.x = a01.x; w.y = a01.y; w.z = a23.x; w.w = a23.y;
        *(ushort4*)&Bs[(p + 0) * 264 + k4] = w;
        a01 = f2bf2(v0.y, v1.y); a23 = f2bf2(v2.y, v3.y);
        w.x = a01.x; w.y = a01.y; w.z = a23.x; w.w = a23.y;
        *(ushort4*)&Bs[(p + 1) * 264 + k4] = w;
        a01 = f2bf2(v0.z, v1.z); a23 = f2bf2(v2.z, v3.z);
        w.x = a01.x; w.y = a01.y; w.z = a23.x; w.w = a23.y;
        *(ushort4*)&Bs[(p + 2) * 264 + k4] = w;
        a01 = f2bf2(v0.w, v1.w); a23 = f2bf2(v2.w, v3.w);
        w.x = a01.x; w.y = a01.y; w.z = a23.x; w.w = a23.y;
        *(ushort4*)&Bs[(p + 3) * 264 + k4] = w;
    }
    __syncthreads();

    const int wave = tid >> 6, lane = tid & 63;
    const int wr = wave * 64;
    const int m = lane & 15, q8 = (lane >> 4) * 8;
    f32x4 acc[4][4];
    #pragma unroll
    for (int a = 0; a < 4; ++a)
        #pragma unroll
        for (int q = 0; q < 4; ++q) acc[a][q] = (f32x4){0.f, 0.f, 0.f, 0.f};

    #pragma unroll
    for (int kk = 0; kk < 8; ++kk) {
        short8 af[4], bfv[4];
        #pragma unroll
        for (int a = 0; a < 4; ++a)
            af[a] = *(const short8*)&Tb[(long)(wr + a * 16 + m) * 256 + kk * 32 + q8];
        #pragma unroll
        for (int q = 0; q < 4; ++q)
            bfv[q] = *(const short8*)&Bs[(q * 16 + m) * 264 + kk * 32 + q8];
        #pragma unroll
        for (int a = 0; a < 4; ++a)
            #pragma unroll
            for (int q = 0; q < 4; ++q)
                acc[a][q] = MFMA16(af[a], bfv[q], acc[a][q]);
    }

    const int rq = (lane >> 4) * 4;
    #pragma unroll
    for (int a = 0; a < 4; ++a) {
        #pragma unroll
        for (int reg = 0; reg < 4; ++reg) {
            const int row = wr + a * 16 + rq + reg;
            const float off_ = SCALEV * (Acc[ACC_VG + b * 256 + row]
                                         + Acc[ACC_U + b * 256 + row] * dkq
                                         + cvec[512 + row] * (dwqb + 4096.0f * dkq));
            float* orow = &out[((long)b * CC + row) * NPIX + p0];
            #pragma unroll
            for (int q = 0; q < 4; ++q)
                orow[q * 16 + m] = acc[a][q][reg] + off_;
        }
    }
}

extern "C" void kernel_launch(void* const* d_in, const int* in_sizes, int n_in,
                              void* d_out, int out_size, void* d_ws, size_t ws_size,
                              hipStream_t stream) {
    const float* x     = (const float*)d_in[0];
    const float* Wq    = (const float*)d_in[1];
    const float* bq    = (const float*)d_in[2];
    const float* gq    = (const float*)d_in[3];
    const float* betaq = (const float*)d_in[4];
    const float* Wk    = (const float*)d_in[5];
    const float* bk    = (const float*)d_in[6];
    const float* gk    = (const float*)d_in[7];
    const float* betak = (const float*)d_in[8];
    const float* Wv    = (const float*)d_in[9];
    const float* bv    = (const float*)d_in[10];
    const float* gv    = (const float*)d_in[11];
    const float* betav = (const float*)d_in[12];
    float* ws = (float*)d_ws;

    float*  Pg   = ws + OFF_PG;
    float*  Sp   = ws + OFF_SP;
    float*  S    = ws + OFF_S;
    float*  Ghat = ws + OFF_GHAT;
    float*  Xbar = ws + OFF_XBAR;
    float*  Wp   = ws + OFF_WP;
    float*  WkTf = ws + OFF_WKTF;
    float*  WvTf = ws + OFF_WVTF;
    float*  cvec = ws + OFF_CVEC;
    float*  Acc  = ws + OFF_ACC;
    ushort* Gbf  = (ushort*)(ws + OFF_GBF);
    ushort* WqT  = (ushort*)(ws + OFF_WQT);
    ushort* WkT  = (ushort*)(ws + OFF_WKT);
    ushort* Wvb  = (ushort*)(ws + OFF_WVB);
    ushort* ZT   = (ushort*)(ws + OFF_ZT);
    ushort* FT   = (ushort*)(ws + OFF_FT);
    ushort* Tbf  = (ushort*)(ws + OFF_TBF);

    gram_mfma<<<dim3(16, 8, 3), 256, 0, stream>>>(x, Pg, Sp, Ghat, Acc);
    reduce_mirror<<<385, 256, 0, stream>>>(Pg, Sp, Gbf, Ghat, S, Xbar);
    stats_quad<<<dim3(64, 3), 256, 0, stream>>>(Wq, Wk, Wv, Ghat, Xbar,
                                                bq, gq, betaq, bk, gk, betak,
                                                bv, gv, betav, Wp, cvec,
                                                WqT, WkT, Wvb, WkTf, WvTf);
    zmida<<<40, 256, 0, stream>>>(WkT, WqT, ZT, Wp, WkTf, WvTf, S, cvec, Acc);
    bcF2<<<97, 256, 0, stream>>>(Gbf, ZT, FT, Wp, cvec, Acc);
    tvg<<<64, 256, 0, stream>>>(Wvb, FT, Tbf, WvTf, cvec, Acc);
    out_mfma<<<dim3(64, 8), 256, 0, stream>>>(Tbf, x, Acc, cvec, (float*)d_out);
}